// Round 1
// baseline (595.806 us; speedup 1.0000x reference)
//
#include <hip/hip_runtime.h>
#include <hip/hip_bf16.h>
#include <stdint.h>

// ---------------------------------------------------------------------------
// AbsorberPathAggregator — MI355X (gfx950)
// Sizes: B=32, N=64, H=128, RBF=32, GH=256, SC=64, OUT=256, PMAX=256, NE=64
// ---------------------------------------------------------------------------

#define CUTOFF_F 6.0f

typedef __bf16 bf16x8_t __attribute__((ext_vector_type(8)));
typedef float  f32x4_t  __attribute__((ext_vector_type(4)));

union FragU { bf16x8_t v; uint32_t u[4]; uint2 d2[2]; };

__device__ __forceinline__ float silu_f(float x){ return x / (1.0f + __expf(-x)); }

__device__ __forceinline__ uint16_t f2bf(float a){
    union { __hip_bfloat16 h; uint16_t u; } c; c.h = __float2bfloat16(a); return c.u;
}
__device__ __forceinline__ uint32_t pk2(float a, float b){
    union { __hip_bfloat162 h; uint32_t u; } c;
    c.h = __float22bfloat162_rn(make_float2(a, b));
    return c.u;
}
// load an 8-bf16 MFMA fragment from LDS: two 8B reads (k0..k0+3, k0+16..k0+19)
__device__ __forceinline__ void frag_lds(FragU& f, const char* base, uint32_t b0, uint32_t b1){
    f.d2[0] = *(const uint2*)(base + b0);
    f.d2[1] = *(const uint2*)(base + b1);
}
__device__ __forceinline__ void frag_g(FragU& f, const uint16_t* p){
    f.d2[0] = *(const uint2*)(p);
    f.d2[1] = *(const uint2*)(p + 16);
}

// ---------------------------------------------------------------------------
// K0a: T_A[101][256], T_B[101][256], T_C[64][256] (f32)
// ---------------------------------------------------------------------------
__global__ void k_tables(const float* __restrict__ z_emb, const float* __restrict__ e_feat,
                         const float* __restrict__ pe_W1, const float* __restrict__ pe_b1,
                         float* __restrict__ T_A, float* __restrict__ T_B, float* __restrict__ T_C){
    int row = blockIdx.x; int c = threadIdx.x;
    if (row < 101){
        const float* e = z_emb + row*32;
        float s = 0.f;
        #pragma unroll
        for (int d = 0; d < 32; d++) s += e[d] * pe_W1[d*256 + c];
        T_A[row*256 + c] = s;
    } else if (row < 202){
        const float* e = z_emb + (row-101)*32;
        float s = 0.f;
        #pragma unroll
        for (int d = 0; d < 32; d++) s += e[d] * pe_W1[(32+d)*256 + c];
        T_B[(row-101)*256 + c] = s;
    } else {
        int n = row - 202;
        const float* e = e_feat + n*32;
        float s = pe_b1[c];
        #pragma unroll
        for (int d = 0; d < 32; d++) s += e[d] * pe_W1[(64+d)*256 + c];
        T_C[n*256 + c] = s;
    }
}

// ---------------------------------------------------------------------------
// K0b: weight prep -> bf16 transposed. W2t is XOR-swizzled (LDS-resident in k_pe),
// the rest are plain [out][in] for per-lane global fragment reads.
// ---------------------------------------------------------------------------
__global__ void k_prep(const float* __restrict__ pe_W2, const float* __restrict__ pe_W3,
                       const float* __restrict__ gm_W1, const float* __restrict__ gm_W2,
                       const float* __restrict__ gm_W3,
                       uint16_t* __restrict__ W2t, uint16_t* __restrict__ W3t,
                       uint16_t* __restrict__ gW1t, uint16_t* __restrict__ gW2t,
                       uint16_t* __restrict__ gW3t){
    int idx = blockIdx.x*256 + threadIdx.x;
    if (idx < 65536){                                   // W2t swizzled [c][k]
        int k = idx >> 8, c = idx & 255;
        uint32_t byte = (uint32_t)c*512u + (((uint32_t)(2*k)) ^ (((uint32_t)(c&7))<<4));
        *(uint16_t*)((char*)W2t + byte) = f2bf(pe_W2[idx]);
    } else if (idx < 65536+16384){                      // W3t [s][k]
        int i = idx - 65536; int k = i >> 6, s = i & 63;
        W3t[s*256 + k] = f2bf(pe_W3[i]);
    } else if (idx < 65536+16384+98304){                // gW1t [c][384], zero-pad k>=353
        int i = idx - (65536+16384); int k = i >> 8, c = i & 255;
        float v = (k < 353) ? gm_W1[k*256 + c] : 0.0f;
        gW1t[c*384 + k] = f2bf(v);
    } else if (idx < 65536+16384+98304+65536){          // gW2t [c][k]
        int i = idx - (65536+16384+98304); int k = i >> 8, c = i & 255;
        gW2t[c*256 + k] = f2bf(gm_W2[i]);
    } else {                                            // gW3t [s][k]
        int i = idx - (65536+16384+98304+65536); int k = i >> 6, s = i & 63;
        gW3t[s*256 + k] = f2bf(gm_W3[i]);
    }
}

// ---------------------------------------------------------------------------
// K1: pair selection per batch (1 wave). First PMAX valid (j<k) pairs, lex order.
// ---------------------------------------------------------------------------
__global__ void k_pairs(const float* __restrict__ pos, const int* __restrict__ mask,
                        const int* __restrict__ zin, const int* __restrict__ aidx,
                        int* __restrict__ jA, int* __restrict__ kA,
                        int* __restrict__ zjA, int* __restrict__ zkA,
                        float* __restrict__ pmask, float* __restrict__ pgeo){
    const int b = blockIdx.x;
    const int j = threadIdx.x;
    const int ai = aidx[0];
    __shared__ float sx[64], sy[64], sz[64], sr[64];

    // probe: was the bool mask uploaded as int32 (values {0,1}) or as bytes?
    bool okp = true;
    #pragma unroll
    for (int i = 0; i < 2; i++){
        int v = mask[j + 64*i];   // first 512 bytes only — safe for either layout
        okp = okp && (v == 0 || v == 1);
    }
    const bool isI32 = (__all(okp) != 0);

    float p0x = pos[(b*64+ai)*3+0];
    float p0y = pos[(b*64+ai)*3+1];
    float p0z = pos[(b*64+ai)*3+2];
    float x  = pos[(b*64+j)*3+0];
    float y  = pos[(b*64+j)*3+1];
    float zc = pos[(b*64+j)*3+2];
    float dx = x-p0x, dy = y-p0y, dz = zc-p0z;
    float r = sqrtf(dx*dx + dy*dy + dz*dz + 1e-12f);
    bool mv = isI32 ? (mask[b*64+j] != 0) : (((const unsigned char*)mask)[b*64+j] != 0);
    bool valid = mv && (j != ai) && (r <= CUTOFF_F);
    sx[j]=x; sy[j]=y; sz[j]=zc; sr[j]=r;
    unsigned long long vm = __ballot(valid);
    __syncthreads();

    int z0 = zin[b*64 + 0];
    for (int s = j; s < 256; s += 64){
        int slot = b*256 + s;
        jA[slot]=0; kA[slot]=0; zjA[slot]=z0; zkA[slot]=z0;
        pmask[slot]=0.0f;
        pgeo[slot*4+0]=0.0f; pgeo[slot*4+1]=0.0f; pgeo[slot*4+2]=0.0f; pgeo[slot*4+3]=0.0f;
    }
    __syncthreads();

    int prefix = 0;
    for (int i = 0; i < 63; i++){
        if (i < j && ((vm>>i)&1ull)) prefix += __popcll(vm >> (i+1));
    }
    if (valid){
        int rank = prefix;
        for (int k = j+1; k < 64; k++){
            if ((vm>>k)&1ull){
                if (rank < 256){
                    int slot = b*256 + rank;
                    jA[slot]=j; kA[slot]=k;
                    zjA[slot]=zin[b*64+j]; zkA[slot]=zin[b*64+k];
                    pmask[slot]=1.0f;
                    float vkx=sx[k]-p0x, vky=sy[k]-p0y, vkz=sz[k]-p0z;
                    float jkx=sx[k]-x,   jky=sy[k]-y,   jkz=sz[k]-zc;
                    float rjk = sqrtf(jkx*jkx + jky*jky + jkz*jkz + 1e-12f);
                    float r0k = sr[k];
                    float inj = 1.0f/fmaxf(r,   1e-8f);
                    float ink = 1.0f/fmaxf(r0k, 1e-8f);
                    float cs = (dx*vkx + dy*vky + dz*vkz) * inj * ink;
                    cs = fminf(fmaxf(cs, -1.0f), 1.0f);
                    pgeo[slot*4+0]=r; pgeo[slot*4+1]=r0k; pgeo[slot*4+2]=rjk; pgeo[slot*4+3]=cs;
                }
                rank++;
            }
        }
    }
}

// ---------------------------------------------------------------------------
// K2: geom MLP (353->256->256->64), 32 pair-rows per block, MFMA 16x16x32 bf16.
// A-tiles from XOR-swizzled LDS; B fragments read straight from L2-hot globals.
// ---------------------------------------------------------------------------
__launch_bounds__(256, 2)
__global__ void k_geom(const float* __restrict__ h, const int* __restrict__ jA, const int* __restrict__ kA,
                       const float* __restrict__ pmask, const float* __restrict__ pgeo,
                       const uint16_t* __restrict__ gW1t, const uint16_t* __restrict__ gW2t,
                       const uint16_t* __restrict__ gW3t,
                       const float* __restrict__ gb1, const float* __restrict__ gb2,
                       const float* __restrict__ gb3, float* __restrict__ ggeom){
    __shared__ __align__(16) char X0[32*768];   // 24576 B: features / later X2 [32][512B]
    __shared__ __align__(16) char X1[32*512];   // 16384 B
    const int b = blockIdx.x >> 3, pc = blockIdx.x & 7;
    const int tid = threadIdx.x;
    const int w = tid >> 6, l = tid & 63, l15 = l & 15, l4 = l >> 4;
    const int pbase = b*256 + pc*32;
    const float GAMMA = 26.694444444444443f;    // (31/6)^2, matches 1/(delta^2+1e-12)
    const float STEP  = 0.19354838709677419f;   // 6/31

    // ---- build X0 [32 rows][384 cols] bf16 (swizzled) ----
    for (int e = tid; e < 32*96; e += 256){
        int row = e / 96;
        int q = e - row*96;        // quad of 4 features
        int slot = pbase + row;
        float f0=0.f, f1=0.f, f2=0.f, f3=0.f;
        if (q < 64){
            int idxa = (q < 32) ? jA[slot] : kA[slot];
            int koff = (q < 32) ? (q*4) : (q*4 - 128);
            const float* hp = h + ((b*64 + idxa)*128 + koff);
            f0=hp[0]; f1=hp[1]; f2=hp[2]; f3=hp[3];
        } else if (q < 88){
            int kk = q*4 - 256;
            int reg = kk >> 5;      // 0: r0j, 1: r0k, 2: rjk
            int t0 = kk & 31;
            float rr = fminf(pgeo[slot*4 + reg], CUTOFF_F);
            float d0 = rr - (float)(t0+0)*STEP; f0 = __expf(-GAMMA*d0*d0);
            float d1 = rr - (float)(t0+1)*STEP; f1 = __expf(-GAMMA*d1*d1);
            float d2 = rr - (float)(t0+2)*STEP; f2 = __expf(-GAMMA*d2*d2);
            float d3 = rr - (float)(t0+3)*STEP; f3 = __expf(-GAMMA*d3*d3);
        } else if (q == 88){
            f0 = pgeo[slot*4+3];    // cosang; rest of row is zero pad (k=353..383)
        }
        uint32_t byte = (uint32_t)row*768u + (((uint32_t)(8*q)) ^ (((uint32_t)(row&7))<<4));
        *(uint2*)(X0 + byte) = make_uint2(pk2(f0,f1), pk2(f2,f3));
    }
    __syncthreads();

    // ---- GEMM1: [32 x 256], K=384 ----
    f32x4_t a1[2][4];
    #pragma unroll
    for (int mt=0; mt<2; mt++)
        #pragma unroll
        for (int nt=0; nt<4; nt++){ a1[mt][nt][0]=0;a1[mt][nt][1]=0;a1[mt][nt][2]=0;a1[mt][nt][3]=0; }
    #pragma unroll 4
    for (int kt=0; kt<12; kt++){
        int k0 = 4*l4 + 32*kt;
        FragU A[2];
        #pragma unroll
        for (int mt=0; mt<2; mt++){
            int row = 16*mt + l15;
            uint32_t sw = ((uint32_t)(row&7))<<4;
            frag_lds(A[mt], X0, (uint32_t)row*768u + (((uint32_t)(2*k0))^sw),
                                (uint32_t)row*768u + (((uint32_t)(2*k0+32))^sw));
        }
        #pragma unroll
        for (int nt=0; nt<4; nt++){
            int c = 64*w + 16*nt + l15;
            FragU Bf; frag_g(Bf, gW1t + c*384 + k0);
            #pragma unroll
            for (int mt=0; mt<2; mt++)
                a1[mt][nt] = __builtin_amdgcn_mfma_f32_16x16x32_bf16(A[mt].v, Bf.v, a1[mt][nt], 0,0,0);
        }
    }
    #pragma unroll
    for (int nt=0; nt<4; nt++){
        int c = 64*w + 16*nt + l15;
        float bias = gb1[c];
        #pragma unroll
        for (int mt=0; mt<2; mt++)
            #pragma unroll
            for (int r=0; r<4; r++){
                int m = 16*mt + 4*l4 + r;
                float v = silu_f(a1[mt][nt][r] + bias);
                uint32_t byte = (uint32_t)m*512u + (((uint32_t)(2*c)) ^ (((uint32_t)(m&7))<<4));
                *(uint16_t*)(X1 + byte) = f2bf(v);
            }
    }
    __syncthreads();

    // ---- GEMM2: [32 x 256], K=256 ----
    f32x4_t a2[2][4];
    #pragma unroll
    for (int mt=0; mt<2; mt++)
        #pragma unroll
        for (int nt=0; nt<4; nt++){ a2[mt][nt][0]=0;a2[mt][nt][1]=0;a2[mt][nt][2]=0;a2[mt][nt][3]=0; }
    #pragma unroll 4
    for (int kt=0; kt<8; kt++){
        int k0 = 4*l4 + 32*kt;
        FragU A[2];
        #pragma unroll
        for (int mt=0; mt<2; mt++){
            int row = 16*mt + l15;
            uint32_t sw = ((uint32_t)(row&7))<<4;
            frag_lds(A[mt], X1, (uint32_t)row*512u + (((uint32_t)(2*k0))^sw),
                                (uint32_t)row*512u + (((uint32_t)(2*k0+32))^sw));
        }
        #pragma unroll
        for (int nt=0; nt<4; nt++){
            int c = 64*w + 16*nt + l15;
            FragU Bf; frag_g(Bf, gW2t + c*256 + k0);
            #pragma unroll
            for (int mt=0; mt<2; mt++)
                a2[mt][nt] = __builtin_amdgcn_mfma_f32_16x16x32_bf16(A[mt].v, Bf.v, a2[mt][nt], 0,0,0);
        }
    }
    #pragma unroll
    for (int nt=0; nt<4; nt++){
        int c = 64*w + 16*nt + l15;
        float bias = gb2[c];
        #pragma unroll
        for (int mt=0; mt<2; mt++)
            #pragma unroll
            for (int r=0; r<4; r++){
                int m = 16*mt + 4*l4 + r;
                float v = silu_f(a2[mt][nt][r] + bias);
                uint32_t byte = (uint32_t)m*512u + (((uint32_t)(2*c)) ^ (((uint32_t)(m&7))<<4));
                *(uint16_t*)(X0 + byte) = f2bf(v);   // X2 lives in X0 buffer, stride 512B
            }
    }
    __syncthreads();

    // ---- GEMM3: [32 x 64], K=256; wave w owns cols 16w..16w+15 ----
    f32x4_t a3[2];
    a3[0][0]=0;a3[0][1]=0;a3[0][2]=0;a3[0][3]=0;
    a3[1][0]=0;a3[1][1]=0;a3[1][2]=0;a3[1][3]=0;
    int s = 16*w + l15;
    #pragma unroll 4
    for (int kt=0; kt<8; kt++){
        int k0 = 4*l4 + 32*kt;
        FragU Bf; frag_g(Bf, gW3t + s*256 + k0);
        #pragma unroll
        for (int mt=0; mt<2; mt++){
            int row = 16*mt + l15;
            uint32_t sw = ((uint32_t)(row&7))<<4;
            FragU A;
            frag_lds(A, X0, (uint32_t)row*512u + (((uint32_t)(2*k0))^sw),
                            (uint32_t)row*512u + (((uint32_t)(2*k0+32))^sw));
            a3[mt] = __builtin_amdgcn_mfma_f32_16x16x32_bf16(A.v, Bf.v, a3[mt], 0,0,0);
        }
    }
    float bias3 = gb3[s];
    #pragma unroll
    for (int mt=0; mt<2; mt++)
        #pragma unroll
        for (int r=0; r<4; r++){
            int prow = 16*mt + 4*l4 + r;
            int slot = pbase + prow;
            ggeom[slot*64 + s] = (a3[mt][r] + bias3) * pmask[slot];
        }
}

// ---------------------------------------------------------------------------
// K3: main pe-MLP. One block = (batch b, chunk of 32 pairs). W2 resident in LDS
// (128 KiB swizzled bf16), X1/X2 bounce buffer 32 KiB. W3 fragments in VGPRs.
// Per pair: X1=silu(T_A[zj]+T_B[zk]+T_C[n]) -> GEMM1(64x256x256) -> silu ->
// GEMM2(64x64x256) -> (+b3) * g_geom, accumulate in registers over pairs.
// ---------------------------------------------------------------------------
__launch_bounds__(256, 1)
__global__ void k_pe(const float* __restrict__ T_A, const float* __restrict__ T_B,
                     const float* __restrict__ T_C,
                     const uint16_t* __restrict__ W2t, const uint16_t* __restrict__ W3t,
                     const float* __restrict__ b2, const float* __restrict__ b3,
                     const int* __restrict__ zjA, const int* __restrict__ zkA,
                     const float* __restrict__ ggeom, float* __restrict__ agg){
    extern __shared__ __align__(16) char smem[];
    char* W2s = smem;              // 131072 B, swizzled [c][512B]
    char* Xs  = smem + 131072;     // 32768 B, [64][512B] (X1 then X2)
    const int b = blockIdx.x >> 3, pc = blockIdx.x & 7;
    const int tid = threadIdx.x;
    const int w = tid >> 6, l = tid & 63, l15 = l & 15, l4 = l >> 4;

    // stage W2 into LDS (pre-swizzled in workspace -> linear copy)
    {
        const uint4* src = (const uint4*)W2t;
        uint4* dst = (uint4*)W2s;
        for (int i = tid; i < 131072/16; i += 256) dst[i] = src[i];
    }
    // preload W3 fragments (loop-invariant across pairs): nt in [0,4), kt in [0,8)
    FragU w3f[4][8];
    #pragma unroll
    for (int nt=0; nt<4; nt++)
        #pragma unroll
        for (int kt=0; kt<8; kt++){
            int s = 16*nt + l15;
            int k0 = 4*l4 + 32*kt;
            frag_g(w3f[nt][kt], W3t + s*256 + k0);
        }
    float b2v[4], b3v[4];
    #pragma unroll
    for (int nt=0; nt<4; nt++){
        b2v[nt] = b2[64*w + 16*nt + l15];
        b3v[nt] = b3[16*nt + l15];
    }
    f32x4_t pacc[4];
    #pragma unroll
    for (int nt=0; nt<4; nt++){ pacc[nt][0]=0;pacc[nt][1]=0;pacc[nt][2]=0;pacc[nt][3]=0; }
    __syncthreads();

    const int kb = tid & 63, nset = tid >> 6;   // X1-build roles
    const int k4 = kb*4;

    for (int pi = 0; pi < 32; pi++){
        const int slot = b*256 + pc*32 + pi;
        // ---- build X1 = silu(T_A[zj]+T_B[zk]+T_C[n]) -> Xs (bf16, swizzled) ----
        {
            int zj = zjA[slot], zk = zkA[slot];
            float4 ta = *(const float4*)(T_A + zj*256 + k4);
            float4 tb = *(const float4*)(T_B + zk*256 + k4);
            float bx = ta.x+tb.x, by = ta.y+tb.y, bz = ta.z+tb.z, bw = ta.w+tb.w;
            #pragma unroll
            for (int i = 0; i < 16; i++){
                int n = nset*16 + i;
                float4 tc = *(const float4*)(T_C + n*256 + k4);
                float v0 = silu_f(bx+tc.x), v1 = silu_f(by+tc.y);
                float v2 = silu_f(bz+tc.z), v3 = silu_f(bw+tc.w);
                uint32_t byte = (uint32_t)n*512u + (((uint32_t)(8*kb)) ^ (((uint32_t)(n&7))<<4));
                *(uint2*)(Xs + byte) = make_uint2(pk2(v0,v1), pk2(v2,v3));
            }
        }
        __syncthreads();
        // ---- GEMM1: [64 x 256], K=256; wave w owns cols 64w..64w+63 ----
        f32x4_t a1[4][4];
        #pragma unroll
        for (int mt=0; mt<4; mt++)
            #pragma unroll
            for (int nt=0; nt<4; nt++){ a1[mt][nt][0]=0;a1[mt][nt][1]=0;a1[mt][nt][2]=0;a1[mt][nt][3]=0; }
        #pragma unroll 2
        for (int kt=0; kt<8; kt++){
            int k0 = 4*l4 + 32*kt;
            FragU A[4];
            #pragma unroll
            for (int mt=0; mt<4; mt++){
                int row = 16*mt + l15;
                uint32_t sw = ((uint32_t)(row&7))<<4;
                frag_lds(A[mt], Xs, (uint32_t)row*512u + (((uint32_t)(2*k0))^sw),
                                    (uint32_t)row*512u + (((uint32_t)(2*k0+32))^sw));
            }
            #pragma unroll
            for (int nt=0; nt<4; nt++){
                int c = 64*w + 16*nt + l15;
                uint32_t sw = ((uint32_t)(c&7))<<4;
                FragU Bf;
                frag_lds(Bf, W2s, (uint32_t)c*512u + (((uint32_t)(2*k0))^sw),
                                  (uint32_t)c*512u + (((uint32_t)(2*k0+32))^sw));
                #pragma unroll
                for (int mt=0; mt<4; mt++)
                    a1[mt][nt] = __builtin_amdgcn_mfma_f32_16x16x32_bf16(A[mt].v, Bf.v, a1[mt][nt], 0,0,0);
            }
        }
        __syncthreads();   // everyone done reading X1
        // ---- silu + store X2 (bf16) into Xs ----
        #pragma unroll
        for (int nt=0; nt<4; nt++){
            int c = 64*w + 16*nt + l15;
            #pragma unroll
            for (int mt=0; mt<4; mt++)
                #pragma unroll
                for (int r=0; r<4; r++){
                    int m = 16*mt + 4*l4 + r;
                    float v = silu_f(a1[mt][nt][r] + b2v[nt]);
                    uint32_t byte = (uint32_t)m*512u + (((uint32_t)(2*c)) ^ (((uint32_t)(m&7))<<4));
                    *(uint16_t*)(Xs + byte) = f2bf(v);
                }
        }
        __syncthreads();
        // ---- GEMM2: [64 x 64], K=256; wave w owns rows 16w..16w+15 ----
        f32x4_t a2[4];
        #pragma unroll
        for (int nt=0; nt<4; nt++){ a2[nt][0]=0;a2[nt][1]=0;a2[nt][2]=0;a2[nt][3]=0; }
        #pragma unroll 2
        for (int kt=0; kt<8; kt++){
            int k0 = 4*l4 + 32*kt;
            int row = 16*w + l15;
            uint32_t sw = ((uint32_t)(row&7))<<4;
            FragU A;
            frag_lds(A, Xs, (uint32_t)row*512u + (((uint32_t)(2*k0))^sw),
                            (uint32_t)row*512u + (((uint32_t)(2*k0+32))^sw));
            #pragma unroll
            for (int nt=0; nt<4; nt++)
                a2[nt] = __builtin_amdgcn_mfma_f32_16x16x32_bf16(A.v, w3f[nt][kt].v, a2[nt], 0,0,0);
        }
        // ---- fuse: (g_elem) * g_geom, accumulate over pairs in registers ----
        #pragma unroll
        for (int nt=0; nt<4; nt++){
            float gg = ggeom[slot*64 + 16*nt + l15];
            #pragma unroll
            for (int r=0; r<4; r++)
                pacc[nt][r] += (a2[nt][r] + b3v[nt]) * gg;
        }
        __syncthreads();   // before next pair's X1 build overwrites Xs
    }
    // ---- commit to agg ----
    #pragma unroll
    for (int nt=0; nt<4; nt++)
        #pragma unroll
        for (int r=0; r<4; r++){
            int n = 16*w + 4*l4 + r;
            int s = 16*nt + l15;
            atomicAdd(&agg[(b*64 + n)*64 + s], pacc[nt][r]);
        }
}

// ---------------------------------------------------------------------------
// K4: out = silu(agg @ op_W1 + b1) @ op_W2 + b2   (f32 VALU, tiny)
// ---------------------------------------------------------------------------
__global__ void k_out(const float* __restrict__ agg, const float* __restrict__ W1,
                      const float* __restrict__ bb1, const float* __restrict__ W2,
                      const float* __restrict__ bb2, float* __restrict__ out){
    __shared__ float sag[16][64];
    __shared__ float shid[16][256];
    const int row0 = blockIdx.x * 16;
    const int tid = threadIdx.x;
    for (int i = tid; i < 16*64; i += 256) sag[i>>6][i&63] = agg[row0*64 + i];
    __syncthreads();
    float a[16];
    #pragma unroll
    for (int i=0;i<16;i++) a[i] = bb1[tid];
    for (int k=0;k<64;k++){
        float wv = W1[k*256 + tid];
        #pragma unroll
        for (int i=0;i<16;i++) a[i] += sag[i][k]*wv;
    }
    #pragma unroll
    for (int i=0;i<16;i++) shid[i][tid] = silu_f(a[i]);
    __syncthreads();
    float o[16];
    #pragma unroll
    for (int i=0;i<16;i++) o[i] = bb2[tid];
    for (int c=0;c<256;c++){
        float wv = W2[c*256 + tid];
        #pragma unroll
        for (int i=0;i<16;i++) o[i] += shid[i][c]*wv;
    }
    #pragma unroll
    for (int i=0;i<16;i++) out[(row0+i)*256 + tid] = o[i];
}

// ---------------------------------------------------------------------------
extern "C" void kernel_launch(void* const* d_in, const int* in_sizes, int n_in,
                              void* d_out, int out_size, void* d_ws, size_t ws_size,
                              hipStream_t stream){
    const float* h      = (const float*)d_in[0];
    const int*   z      = (const int*)  d_in[1];
    const float* pos    = (const float*)d_in[2];
    const int*   mask   = (const int*)  d_in[3];
    const float* e_feat = (const float*)d_in[4];
    const float* z_emb  = (const float*)d_in[5];
    const float* gm_W1  = (const float*)d_in[6];
    const float* gm_b1  = (const float*)d_in[7];
    const float* gm_W2  = (const float*)d_in[8];
    const float* gm_b2  = (const float*)d_in[9];
    const float* gm_W3  = (const float*)d_in[10];
    const float* gm_b3  = (const float*)d_in[11];
    const float* pe_W1  = (const float*)d_in[12];
    const float* pe_b1  = (const float*)d_in[13];
    const float* pe_W2  = (const float*)d_in[14];
    const float* pe_b2  = (const float*)d_in[15];
    const float* pe_W3  = (const float*)d_in[16];
    const float* pe_b3  = (const float*)d_in[17];
    const float* op_W1  = (const float*)d_in[18];
    const float* op_b1  = (const float*)d_in[19];
    const float* op_W2  = (const float*)d_in[20];
    const float* op_b2  = (const float*)d_in[21];
    const int*   aidx   = (const int*)  d_in[22];
    float* out = (float*)d_out;
    char* ws = (char*)d_ws;

    // workspace layout (bytes)
    float*    T_A   = (float*)   (ws + 0);        // 101*256*4 = 103424
    float*    T_B   = (float*)   (ws + 103424);
    float*    T_C   = (float*)   (ws + 206848);   // 64*256*4 = 65536
    uint16_t* W2t   = (uint16_t*)(ws + 272384);   // 131072 (swizzled)
    uint16_t* W3t   = (uint16_t*)(ws + 403456);   // 32768
    uint16_t* gW1t  = (uint16_t*)(ws + 436224);   // 196608
    uint16_t* gW2t  = (uint16_t*)(ws + 632832);   // 131072
    uint16_t* gW3t  = (uint16_t*)(ws + 763904);   // 32768
    int*      jA    = (int*)     (ws + 796672);   // 32768
    int*      kA    = (int*)     (ws + 829440);
    int*      zjA   = (int*)     (ws + 862208);
    int*      zkA   = (int*)     (ws + 894976);
    float*    pmask = (float*)   (ws + 927744);
    float*    pgeo  = (float*)   (ws + 960512);   // 131072
    float*    ggeom = (float*)   (ws + 1091584);  // 2097152
    float*    agg   = (float*)   (ws + 3188736);  // 524288

    hipFuncSetAttribute((const void*)k_pe, hipFuncAttributeMaxDynamicSharedMemorySize, 163840);

    k_tables<<<266, 256, 0, stream>>>(z_emb, e_feat, pe_W1, pe_b1, T_A, T_B, T_C);
    k_prep<<<1024, 256, 0, stream>>>(pe_W2, pe_W3, gm_W1, gm_W2, gm_W3, W2t, W3t, gW1t, gW2t, gW3t);
    k_pairs<<<32, 64, 0, stream>>>(pos, mask, z, aidx, jA, kA, zjA, zkA, pmask, pgeo);
    hipMemsetAsync(agg, 0, 32*64*64*4, stream);
    k_geom<<<256, 256, 0, stream>>>(h, jA, kA, pmask, pgeo, gW1t, gW2t, gW3t,
                                    gm_b1, gm_b2, gm_b3, ggeom);
    k_pe<<<256, 256, 163840, stream>>>(T_A, T_B, T_C, W2t, W3t, pe_b2, pe_b3,
                                       zjA, zkA, ggeom, agg);
    k_out<<<128, 256, 0, stream>>>(agg, op_W1, op_b1, op_W2, op_b2, out);
}

// Round 2
// 565.028 us; speedup vs baseline: 1.0545x; 1.0545x over previous
//
#include <hip/hip_runtime.h>
#include <hip/hip_bf16.h>
#include <stdint.h>

// ---------------------------------------------------------------------------
// AbsorberPathAggregator — MI355X (gfx950)  v2
// Sizes: B=32, N=64, H=128, RBF=32, GH=256, SC=64, OUT=256, PMAX=256, NE=64
// ---------------------------------------------------------------------------

#define CUTOFF_F 6.0f

typedef __bf16 bf16x8_t __attribute__((ext_vector_type(8)));
typedef float  f32x4_t  __attribute__((ext_vector_type(4)));

union FragU { bf16x8_t v; uint32_t u[4]; uint2 d2[2]; uint4 d4; };

// fast silu: x * rcp(1 + exp2(-x*log2e)); HW exp2/rcp, no IEEE divide sequence
__device__ __forceinline__ float silu_f(float x){
    float e = __builtin_amdgcn_exp2f(x * -1.44269504088896f);
    return x * __builtin_amdgcn_rcpf(1.0f + e);
}

__device__ __forceinline__ uint16_t f2bf(float a){
    union { __hip_bfloat16 h; uint16_t u; } c; c.h = __float2bfloat16(a); return c.u;
}
__device__ __forceinline__ uint32_t pk2(float a, float b){
    union { __hip_bfloat162 h; uint32_t u; } c;
    c.h = __float22bfloat162_rn(make_float2(a, b));
    return c.u;
}
// 8-bf16 fragment from LDS: two 8B reads (k0..k0+3, k0+16..k0+19)
__device__ __forceinline__ void frag_lds(FragU& f, const char* base, uint32_t b0, uint32_t b1){
    f.d2[0] = *(const uint2*)(base + b0);
    f.d2[1] = *(const uint2*)(base + b1);
}
// 8-bf16 fragment from packed global: ONE 16B load
__device__ __forceinline__ void frag_gp(FragU& f, const uint16_t* p){
    f.d4 = *(const uint4*)(p);
}

// ---------------------------------------------------------------------------
// K0a: T_A[101][256], T_B[101][256], T_C[64][256] (f32)
// ---------------------------------------------------------------------------
__global__ void k_tables(const float* __restrict__ z_emb, const float* __restrict__ e_feat,
                         const float* __restrict__ pe_W1, const float* __restrict__ pe_b1,
                         float* __restrict__ T_A, float* __restrict__ T_B, float* __restrict__ T_C){
    int row = blockIdx.x; int c = threadIdx.x;
    if (row < 101){
        const float* e = z_emb + row*32;
        float s = 0.f;
        #pragma unroll
        for (int d = 0; d < 32; d++) s += e[d] * pe_W1[d*256 + c];
        T_A[row*256 + c] = s;
    } else if (row < 202){
        const float* e = z_emb + (row-101)*32;
        float s = 0.f;
        #pragma unroll
        for (int d = 0; d < 32; d++) s += e[d] * pe_W1[(32+d)*256 + c];
        T_B[(row-101)*256 + c] = s;
    } else {
        int n = row - 202;
        const float* e = e_feat + n*32;
        float s = pe_b1[c];
        #pragma unroll
        for (int d = 0; d < 32; d++) s += e[d] * pe_W1[(64+d)*256 + c];
        T_C[n*256 + c] = s;
    }
}

// ---------------------------------------------------------------------------
// K0b: weight prep -> bf16 packed fragment-contiguous layouts.
// Layout: [row][kt][32] where the 32 k-values of each K-tile are permuted so
// lane l4 reads its 8-bf16 fragment {k0..k0+3, k0+16..k0+19} as ONE 16B load:
//   packed p = q*8 + j  <->  k = kt*32 + 4q + (j&3) + 16*(j>>2)
// ---------------------------------------------------------------------------
__global__ void k_prep(const float* __restrict__ pe_W2, const float* __restrict__ pe_W3,
                       const float* __restrict__ gm_W1, const float* __restrict__ gm_W2,
                       const float* __restrict__ gm_W3,
                       uint16_t* __restrict__ W2p, uint16_t* __restrict__ W3p,
                       uint16_t* __restrict__ gW1p, uint16_t* __restrict__ gW2p,
                       uint16_t* __restrict__ gW3p){
    int idx = blockIdx.x*256 + threadIdx.x;   // 262144 total
    if (idx < 65536){                                   // W2p [256c][256]
        int d = idx; int c = d >> 8; int r = d & 255;
        int kt = r >> 5, t = r & 31, q = t >> 3, j = t & 7;
        int k = kt*32 + 4*q + (j&3) + ((j>>2)<<4);
        W2p[d] = f2bf(pe_W2[k*256 + c]);
    } else if (idx < 81920){                            // W3p [64s][256]
        int d = idx - 65536; int s = d >> 8; int r = d & 255;
        int kt = r >> 5, t = r & 31, q = t >> 3, j = t & 7;
        int k = kt*32 + 4*q + (j&3) + ((j>>2)<<4);
        W3p[d] = f2bf(pe_W3[k*64 + s]);
    } else if (idx < 180224){                           // gW1p [256c][384], zero-pad k>=353
        int d = idx - 81920; int c = d / 384; int r = d - c*384;
        int kt = r >> 5, t = r & 31, q = t >> 3, j = t & 7;
        int k = kt*32 + 4*q + (j&3) + ((j>>2)<<4);
        float v = (k < 353) ? gm_W1[k*256 + c] : 0.0f;
        gW1p[d] = f2bf(v);
    } else if (idx < 245760){                           // gW2p [256c][256]
        int d = idx - 180224; int c = d >> 8; int r = d & 255;
        int kt = r >> 5, t = r & 31, q = t >> 3, j = t & 7;
        int k = kt*32 + 4*q + (j&3) + ((j>>2)<<4);
        gW2p[d] = f2bf(gm_W2[k*256 + c]);
    } else {                                            // gW3p [64s][256]
        int d = idx - 245760; int s = d >> 8; int r = d & 255;
        int kt = r >> 5, t = r & 31, q = t >> 3, j = t & 7;
        int k = kt*32 + 4*q + (j&3) + ((j>>2)<<4);
        gW3p[d] = f2bf(gm_W3[k*64 + s]);
    }
}

// ---------------------------------------------------------------------------
// K1: pair selection per batch (1 wave). First PMAX valid (j<k) pairs, lex order.
// ---------------------------------------------------------------------------
__global__ void k_pairs(const float* __restrict__ pos, const int* __restrict__ mask,
                        const int* __restrict__ zin, const int* __restrict__ aidx,
                        int* __restrict__ jA, int* __restrict__ kA,
                        int* __restrict__ zjA, int* __restrict__ zkA,
                        float* __restrict__ pmask, float* __restrict__ pgeo){
    const int b = blockIdx.x;
    const int j = threadIdx.x;
    const int ai = aidx[0];
    __shared__ float sx[64], sy[64], sz[64], sr[64];

    bool okp = true;
    #pragma unroll
    for (int i = 0; i < 2; i++){
        int v = mask[j + 64*i];
        okp = okp && (v == 0 || v == 1);
    }
    const bool isI32 = (__all(okp) != 0);

    float p0x = pos[(b*64+ai)*3+0];
    float p0y = pos[(b*64+ai)*3+1];
    float p0z = pos[(b*64+ai)*3+2];
    float x  = pos[(b*64+j)*3+0];
    float y  = pos[(b*64+j)*3+1];
    float zc = pos[(b*64+j)*3+2];
    float dx = x-p0x, dy = y-p0y, dz = zc-p0z;
    float r = sqrtf(dx*dx + dy*dy + dz*dz + 1e-12f);
    bool mv = isI32 ? (mask[b*64+j] != 0) : (((const unsigned char*)mask)[b*64+j] != 0);
    bool valid = mv && (j != ai) && (r <= CUTOFF_F);
    sx[j]=x; sy[j]=y; sz[j]=zc; sr[j]=r;
    unsigned long long vm = __ballot(valid);
    __syncthreads();

    int z0 = zin[b*64 + 0];
    for (int s = j; s < 256; s += 64){
        int slot = b*256 + s;
        jA[slot]=0; kA[slot]=0; zjA[slot]=z0; zkA[slot]=z0;
        pmask[slot]=0.0f;
        pgeo[slot*4+0]=0.0f; pgeo[slot*4+1]=0.0f; pgeo[slot*4+2]=0.0f; pgeo[slot*4+3]=0.0f;
    }
    __syncthreads();

    int prefix = 0;
    for (int i = 0; i < 63; i++){
        if (i < j && ((vm>>i)&1ull)) prefix += __popcll(vm >> (i+1));
    }
    if (valid){
        int rank = prefix;
        for (int k = j+1; k < 64; k++){
            if ((vm>>k)&1ull){
                if (rank < 256){
                    int slot = b*256 + rank;
                    jA[slot]=j; kA[slot]=k;
                    zjA[slot]=zin[b*64+j]; zkA[slot]=zin[b*64+k];
                    pmask[slot]=1.0f;
                    float vkx=sx[k]-p0x, vky=sy[k]-p0y, vkz=sz[k]-p0z;
                    float jkx=sx[k]-x,   jky=sy[k]-y,   jkz=sz[k]-zc;
                    float rjk = sqrtf(jkx*jkx + jky*jky + jkz*jkz + 1e-12f);
                    float r0k = sr[k];
                    float inj = 1.0f/fmaxf(r,   1e-8f);
                    float ink = 1.0f/fmaxf(r0k, 1e-8f);
                    float cs = (dx*vkx + dy*vky + dz*vkz) * inj * ink;
                    cs = fminf(fmaxf(cs, -1.0f), 1.0f);
                    pgeo[slot*4+0]=r; pgeo[slot*4+1]=r0k; pgeo[slot*4+2]=rjk; pgeo[slot*4+3]=cs;
                }
                rank++;
            }
        }
    }
}

// ---------------------------------------------------------------------------
// K2: geom MLP (353->256->256->64). 16 pair-rows per block, 512 blocks (2/CU).
// A-tiles from XOR-swizzled LDS; B fragments: single 16B loads from packed L2.
// ---------------------------------------------------------------------------
__launch_bounds__(256, 2)
__global__ void k_geom(const float* __restrict__ h, const int* __restrict__ jA, const int* __restrict__ kA,
                       const float* __restrict__ pmask, const float* __restrict__ pgeo,
                       const uint16_t* __restrict__ gW1p, const uint16_t* __restrict__ gW2p,
                       const uint16_t* __restrict__ gW3p,
                       const float* __restrict__ gb1, const float* __restrict__ gb2,
                       const float* __restrict__ gb3, float* __restrict__ ggeom){
    __shared__ __align__(16) char X0[16*768];   // 12288 B: features / later X2 [16][512B]
    __shared__ __align__(16) char X1[16*512];   // 8192 B
    const int b = blockIdx.x >> 4, pc = blockIdx.x & 15;
    const int tid = threadIdx.x;
    const int w = tid >> 6, l = tid & 63, l15 = l & 15, l4 = l >> 4;
    const int pbase = b*256 + pc*16;
    const float GAMMA = 26.694444444444443f;    // (31/6)^2
    const float STEP  = 0.19354838709677419f;   // 6/31

    // ---- build X0 [16 rows][384 cols] bf16 (swizzled) ----
    for (int e = tid; e < 16*96; e += 256){
        int row = e / 96;
        int q = e - row*96;
        int slot = pbase + row;
        float f0=0.f, f1=0.f, f2=0.f, f3=0.f;
        if (q < 64){
            int idxa = (q < 32) ? jA[slot] : kA[slot];
            int koff = (q < 32) ? (q*4) : (q*4 - 128);
            const float* hp = h + ((b*64 + idxa)*128 + koff);
            f0=hp[0]; f1=hp[1]; f2=hp[2]; f3=hp[3];
        } else if (q < 88){
            int kk = q*4 - 256;
            int reg = kk >> 5;
            int t0 = kk & 31;
            float rr = fminf(pgeo[slot*4 + reg], CUTOFF_F);
            float d0 = rr - (float)(t0+0)*STEP; f0 = __builtin_amdgcn_exp2f(-GAMMA*d0*d0*1.44269504088896f);
            float d1 = rr - (float)(t0+1)*STEP; f1 = __builtin_amdgcn_exp2f(-GAMMA*d1*d1*1.44269504088896f);
            float d2 = rr - (float)(t0+2)*STEP; f2 = __builtin_amdgcn_exp2f(-GAMMA*d2*d2*1.44269504088896f);
            float d3 = rr - (float)(t0+3)*STEP; f3 = __builtin_amdgcn_exp2f(-GAMMA*d3*d3*1.44269504088896f);
        } else if (q == 88){
            f0 = pgeo[slot*4+3];    // cosang; k=353..383 zero pad
        }
        uint32_t byte = (uint32_t)row*768u + (((uint32_t)(8*q)) ^ (((uint32_t)(row&7))<<4));
        *(uint2*)(X0 + byte) = make_uint2(pk2(f0,f1), pk2(f2,f3));
    }
    __syncthreads();

    // ---- GEMM1: [16 x 256], K=384 ----
    f32x4_t a1[4];
    #pragma unroll
    for (int nt=0; nt<4; nt++){ a1[nt][0]=0;a1[nt][1]=0;a1[nt][2]=0;a1[nt][3]=0; }
    #pragma unroll 3
    for (int kt=0; kt<12; kt++){
        int k0 = 4*l4 + 32*kt;
        int row = l15;
        uint32_t sw = ((uint32_t)(row&7))<<4;
        FragU A;
        frag_lds(A, X0, (uint32_t)row*768u + (((uint32_t)(2*k0))^sw),
                        (uint32_t)row*768u + (((uint32_t)(2*k0+32))^sw));
        FragU Bf[4];
        #pragma unroll
        for (int nt=0; nt<4; nt++)
            frag_gp(Bf[nt], gW1p + (64*w + 16*nt + l15)*384 + kt*32 + l4*8);
        __builtin_amdgcn_s_setprio(1);
        #pragma unroll
        for (int nt=0; nt<4; nt++)
            a1[nt] = __builtin_amdgcn_mfma_f32_16x16x32_bf16(A.v, Bf[nt].v, a1[nt], 0,0,0);
        __builtin_amdgcn_s_setprio(0);
    }
    #pragma unroll
    for (int nt=0; nt<4; nt++){
        int c = 64*w + 16*nt + l15;
        float bias = gb1[c];
        #pragma unroll
        for (int r=0; r<4; r++){
            int m = 4*l4 + r;
            float v = silu_f(a1[nt][r] + bias);
            uint32_t byte = (uint32_t)m*512u + (((uint32_t)(2*c)) ^ (((uint32_t)(m&7))<<4));
            *(uint16_t*)(X1 + byte) = f2bf(v);
        }
    }
    __syncthreads();

    // ---- GEMM2: [16 x 256], K=256 ----
    f32x4_t a2[4];
    #pragma unroll
    for (int nt=0; nt<4; nt++){ a2[nt][0]=0;a2[nt][1]=0;a2[nt][2]=0;a2[nt][3]=0; }
    #pragma unroll 2
    for (int kt=0; kt<8; kt++){
        int k0 = 4*l4 + 32*kt;
        int row = l15;
        uint32_t sw = ((uint32_t)(row&7))<<4;
        FragU A;
        frag_lds(A, X1, (uint32_t)row*512u + (((uint32_t)(2*k0))^sw),
                        (uint32_t)row*512u + (((uint32_t)(2*k0+32))^sw));
        FragU Bf[4];
        #pragma unroll
        for (int nt=0; nt<4; nt++)
            frag_gp(Bf[nt], gW2p + (64*w + 16*nt + l15)*256 + kt*32 + l4*8);
        __builtin_amdgcn_s_setprio(1);
        #pragma unroll
        for (int nt=0; nt<4; nt++)
            a2[nt] = __builtin_amdgcn_mfma_f32_16x16x32_bf16(A.v, Bf[nt].v, a2[nt], 0,0,0);
        __builtin_amdgcn_s_setprio(0);
    }
    #pragma unroll
    for (int nt=0; nt<4; nt++){
        int c = 64*w + 16*nt + l15;
        float bias = gb2[c];
        #pragma unroll
        for (int r=0; r<4; r++){
            int m = 4*l4 + r;
            float v = silu_f(a2[nt][r] + bias);
            uint32_t byte = (uint32_t)m*512u + (((uint32_t)(2*c)) ^ (((uint32_t)(m&7))<<4));
            *(uint16_t*)(X0 + byte) = f2bf(v);   // X2 lives in X0, stride 512B
        }
    }
    __syncthreads();

    // ---- GEMM3: [16 x 64], K=256; wave w owns cols 16w..16w+15 ----
    f32x4_t a3;
    a3[0]=0;a3[1]=0;a3[2]=0;a3[3]=0;
    int s = 16*w + l15;
    #pragma unroll 2
    for (int kt=0; kt<8; kt++){
        int k0 = 4*l4 + 32*kt;
        FragU Bf; frag_gp(Bf, gW3p + s*256 + kt*32 + l4*8);
        int row = l15;
        uint32_t sw = ((uint32_t)(row&7))<<4;
        FragU A;
        frag_lds(A, X0, (uint32_t)row*512u + (((uint32_t)(2*k0))^sw),
                        (uint32_t)row*512u + (((uint32_t)(2*k0+32))^sw));
        a3 = __builtin_amdgcn_mfma_f32_16x16x32_bf16(A.v, Bf.v, a3, 0,0,0);
    }
    float bias3 = gb3[s];
    #pragma unroll
    for (int r=0; r<4; r++){
        int prow = 4*l4 + r;
        int slot = pbase + prow;
        ggeom[slot*64 + s] = (a3[r] + bias3) * pmask[slot];
    }
}

// ---------------------------------------------------------------------------
// K3: main pe-MLP. 512 blocks = (batch b, chunk of 16 pairs); 64 KiB static LDS
// -> 2 blocks/CU. W2/B-frags from packed L2 globals (1x16B each); W3 fragments
// register-resident. Per pair: X1=silu(T_A[zj]+T_B[zk]+T_C[n]) ->
// GEMM1(64x256x256) -> silu -> GEMM2(64x64x256) -> *g_geom, reg-accumulate.
// 2 barriers per pair. Partials to pagg (no atomics).
// ---------------------------------------------------------------------------
__launch_bounds__(256, 2)
__global__ void k_pe(const float* __restrict__ T_A, const float* __restrict__ T_B,
                     const float* __restrict__ T_C,
                     const uint16_t* __restrict__ W2p, const uint16_t* __restrict__ W3p,
                     const float* __restrict__ b2, const float* __restrict__ b3,
                     const int* __restrict__ zjA, const int* __restrict__ zkA,
                     const float* __restrict__ ggeom, float* __restrict__ pagg){
    __shared__ __align__(16) char X1s[64*512];   // 32768
    __shared__ __align__(16) char X2s[64*512];   // 32768
    const int b = blockIdx.x >> 4, pc = blockIdx.x & 15;
    const int tid = threadIdx.x;
    const int w = tid >> 6, l = tid & 63, l15 = l & 15, l4 = l >> 4;

    // W3 fragments: loop-invariant, register-resident (nt4 x kt8, 16B each)
    FragU w3f[4][8];
    #pragma unroll
    for (int nt=0; nt<4; nt++)
        #pragma unroll
        for (int kt=0; kt<8; kt++)
            frag_gp(w3f[nt][kt], W3p + (16*nt + l15)*256 + kt*32 + l4*8);
    float b2v[4], b3v[4];
    #pragma unroll
    for (int nt=0; nt<4; nt++){
        b2v[nt] = b2[64*w + 16*nt + l15];
        b3v[nt] = b3[16*nt + l15];
    }
    f32x4_t pacc[4];
    #pragma unroll
    for (int nt=0; nt<4; nt++){ pacc[nt][0]=0;pacc[nt][1]=0;pacc[nt][2]=0;pacc[nt][3]=0; }

    const int kb = tid & 63, nset = tid >> 6;   // X1-build roles
    const int k4 = kb*4;

    for (int pi = 0; pi < 16; pi++){
        const int slot = b*256 + pc*16 + pi;
        // ---- build X1 = silu(T_A[zj]+T_B[zk]+T_C[n]) -> X1s (bf16, swizzled) ----
        {
            int zj = zjA[slot], zk = zkA[slot];
            float4 ta = *(const float4*)(T_A + zj*256 + k4);
            float4 tb = *(const float4*)(T_B + zk*256 + k4);
            float bx = ta.x+tb.x, by = ta.y+tb.y, bz = ta.z+tb.z, bw = ta.w+tb.w;
            #pragma unroll
            for (int i = 0; i < 16; i++){
                int n = nset*16 + i;
                float4 tc = *(const float4*)(T_C + n*256 + k4);
                float v0 = silu_f(bx+tc.x), v1 = silu_f(by+tc.y);
                float v2 = silu_f(bz+tc.z), v3 = silu_f(bw+tc.w);
                uint32_t byte = (uint32_t)n*512u + (((uint32_t)(8*kb)) ^ (((uint32_t)(i&7))<<4));
                *(uint2*)(X1s + byte) = make_uint2(pk2(v0,v1), pk2(v2,v3));
            }
        }
        __syncthreads();   // bar A: X1 ready
        // ---- GEMM1: [64 x 256], K=256; wave w owns cols 64w..64w+63 ----
        f32x4_t a1[4][4];
        #pragma unroll
        for (int mt=0; mt<4; mt++)
            #pragma unroll
            for (int nt=0; nt<4; nt++){ a1[mt][nt][0]=0;a1[mt][nt][1]=0;a1[mt][nt][2]=0;a1[mt][nt][3]=0; }
        #pragma unroll 2
        for (int kt=0; kt<8; kt++){
            int k0 = 4*l4 + 32*kt;
            FragU Bf[4];
            #pragma unroll
            for (int nt=0; nt<4; nt++)
                frag_gp(Bf[nt], W2p + (64*w + 16*nt + l15)*256 + kt*32 + l4*8);
            FragU A[4];
            #pragma unroll
            for (int mt=0; mt<4; mt++){
                int row = 16*mt + l15;
                uint32_t sw = ((uint32_t)(row&7))<<4;
                frag_lds(A[mt], X1s, (uint32_t)row*512u + (((uint32_t)(2*k0))^sw),
                                     (uint32_t)row*512u + (((uint32_t)(2*k0+32))^sw));
            }
            __builtin_amdgcn_s_setprio(1);
            #pragma unroll
            for (int nt=0; nt<4; nt++)
                #pragma unroll
                for (int mt=0; mt<4; mt++)
                    a1[mt][nt] = __builtin_amdgcn_mfma_f32_16x16x32_bf16(A[mt].v, Bf[nt].v, a1[mt][nt], 0,0,0);
            __builtin_amdgcn_s_setprio(0);
        }
        // ---- silu + store X2 (bf16) into X2s ----
        #pragma unroll
        for (int nt=0; nt<4; nt++){
            int c = 64*w + 16*nt + l15;
            #pragma unroll
            for (int mt=0; mt<4; mt++)
                #pragma unroll
                for (int r=0; r<4; r++){
                    int m = 16*mt + 4*l4 + r;
                    float v = silu_f(a1[mt][nt][r] + b2v[nt]);
                    uint32_t byte = (uint32_t)m*512u + (((uint32_t)(2*c)) ^ (((uint32_t)(m&7))<<4));
                    *(uint16_t*)(X2s + byte) = f2bf(v);
                }
        }
        __syncthreads();   // bar B: X2 ready (also protects X1 for next build)
        // ---- GEMM2: [64 x 64], K=256; wave w owns rows 16w..16w+15 ----
        f32x4_t a2[4];
        #pragma unroll
        for (int nt=0; nt<4; nt++){ a2[nt][0]=0;a2[nt][1]=0;a2[nt][2]=0;a2[nt][3]=0; }
        #pragma unroll 2
        for (int kt=0; kt<8; kt++){
            int k0 = 4*l4 + 32*kt;
            int row = 16*w + l15;
            uint32_t sw = ((uint32_t)(row&7))<<4;
            FragU A;
            frag_lds(A, X2s, (uint32_t)row*512u + (((uint32_t)(2*k0))^sw),
                             (uint32_t)row*512u + (((uint32_t)(2*k0+32))^sw));
            __builtin_amdgcn_s_setprio(1);
            #pragma unroll
            for (int nt=0; nt<4; nt++)
                a2[nt] = __builtin_amdgcn_mfma_f32_16x16x32_bf16(A.v, w3f[nt][kt].v, a2[nt], 0,0,0);
            __builtin_amdgcn_s_setprio(0);
        }
        // ---- fuse: g_elem * g_geom, accumulate over pairs in registers ----
        #pragma unroll
        for (int nt=0; nt<4; nt++){
            float gg = ggeom[slot*64 + 16*nt + l15];
            #pragma unroll
            for (int r=0; r<4; r++)
                pacc[nt][r] += (a2[nt][r] + b3v[nt]) * gg;
        }
    }
    // ---- commit partials (no atomics): pagg[chunk][n][s] ----
    const int chunk = b*16 + pc;
    #pragma unroll
    for (int nt=0; nt<4; nt++)
        #pragma unroll
        for (int r=0; r<4; r++){
            int n = 16*w + 4*l4 + r;
            int s = 16*nt + l15;
            pagg[(chunk*64 + n)*64 + s] = pacc[nt][r];
        }
}

// ---------------------------------------------------------------------------
// K4: agg = sum over 16 chunks; out = silu(agg @ op_W1 + b1) @ op_W2 + b2
// ---------------------------------------------------------------------------
__global__ void k_out(const float* __restrict__ pagg, const float* __restrict__ W1,
                      const float* __restrict__ bb1, const float* __restrict__ W2,
                      const float* __restrict__ bb2, float* __restrict__ out){
    __shared__ float sag[16][64];
    __shared__ float shid[16][256];
    const int row0 = blockIdx.x * 16;   // rows of [B*NE = 2048]
    const int tid = threadIdx.x;
    const int bb = row0 >> 6;           // 16-row block stays within one batch
    for (int i = tid; i < 16*64; i += 256){
        int row = row0 + (i >> 6);
        int nn = row & 63;
        int k = i & 63;
        float acc = 0.f;
        #pragma unroll
        for (int pcc = 0; pcc < 16; pcc++)
            acc += pagg[((bb*16 + pcc)*64 + nn)*64 + k];
        sag[i>>6][k] = acc;
    }
    __syncthreads();
    float a[16];
    #pragma unroll
    for (int i=0;i<16;i++) a[i] = bb1[tid];
    for (int k=0;k<64;k++){
        float wv = W1[k*256 + tid];
        #pragma unroll
        for (int i=0;i<16;i++) a[i] += sag[i][k]*wv;
    }
    #pragma unroll
    for (int i=0;i<16;i++) shid[i][tid] = silu_f(a[i]);
    __syncthreads();
    float o[16];
    #pragma unroll
    for (int i=0;i<16;i++) o[i] = bb2[tid];
    for (int c=0;c<256;c++){
        float wv = W2[c*256 + tid];
        #pragma unroll
        for (int i=0;i<16;i++) o[i] += shid[i][c]*wv;
    }
    #pragma unroll
    for (int i=0;i<16;i++) out[(row0+i)*256 + tid] = o[i];
}

// ---------------------------------------------------------------------------
extern "C" void kernel_launch(void* const* d_in, const int* in_sizes, int n_in,
                              void* d_out, int out_size, void* d_ws, size_t ws_size,
                              hipStream_t stream){
    const float* h      = (const float*)d_in[0];
    const int*   z      = (const int*)  d_in[1];
    const float* pos    = (const float*)d_in[2];
    const int*   mask   = (const int*)  d_in[3];
    const float* e_feat = (const float*)d_in[4];
    const float* z_emb  = (const float*)d_in[5];
    const float* gm_W1  = (const float*)d_in[6];
    const float* gm_b1  = (const float*)d_in[7];
    const float* gm_W2  = (const float*)d_in[8];
    const float* gm_b2  = (const float*)d_in[9];
    const float* gm_W3  = (const float*)d_in[10];
    const float* gm_b3  = (const float*)d_in[11];
    const float* pe_W1  = (const float*)d_in[12];
    const float* pe_b1  = (const float*)d_in[13];
    const float* pe_W2  = (const float*)d_in[14];
    const float* pe_b2  = (const float*)d_in[15];
    const float* pe_W3  = (const float*)d_in[16];
    const float* pe_b3  = (const float*)d_in[17];
    const float* op_W1  = (const float*)d_in[18];
    const float* op_b1  = (const float*)d_in[19];
    const float* op_W2  = (const float*)d_in[20];
    const float* op_b2  = (const float*)d_in[21];
    const int*   aidx   = (const int*)  d_in[22];
    float* out = (float*)d_out;
    char* ws = (char*)d_ws;

    // workspace layout (bytes, 16B-aligned)
    float*    T_A   = (float*)   (ws + 0);        // 103424
    float*    T_B   = (float*)   (ws + 103424);   // 103424
    float*    T_C   = (float*)   (ws + 206848);   // 65536
    uint16_t* W2p   = (uint16_t*)(ws + 272384);   // 131072
    uint16_t* W3p   = (uint16_t*)(ws + 403456);   // 32768
    uint16_t* gW1p  = (uint16_t*)(ws + 436224);   // 196608
    uint16_t* gW2p  = (uint16_t*)(ws + 632832);   // 131072
    uint16_t* gW3p  = (uint16_t*)(ws + 763904);   // 32768
    int*      jA    = (int*)     (ws + 796672);   // 32768
    int*      kA    = (int*)     (ws + 829440);
    int*      zjA   = (int*)     (ws + 862208);
    int*      zkA   = (int*)     (ws + 894976);
    float*    pmask = (float*)   (ws + 927744);
    float*    pgeo  = (float*)   (ws + 960512);   // 131072
    float*    ggeom = (float*)   (ws + 1091584);  // 2097152
    float*    pagg  = (float*)   (ws + 3188736);  // 8388608 (512 chunks x 64 x 64 f32)

    k_tables<<<266, 256, 0, stream>>>(z_emb, e_feat, pe_W1, pe_b1, T_A, T_B, T_C);
    k_prep<<<1024, 256, 0, stream>>>(pe_W2, pe_W3, gm_W1, gm_W2, gm_W3, W2p, W3p, gW1p, gW2p, gW3p);
    k_pairs<<<32, 64, 0, stream>>>(pos, mask, z, aidx, jA, kA, zjA, zkA, pmask, pgeo);
    k_geom<<<512, 256, 0, stream>>>(h, jA, kA, pmask, pgeo, gW1p, gW2p, gW3p,
                                    gm_b1, gm_b2, gm_b3, ggeom);
    k_pe<<<512, 256, 0, stream>>>(T_A, T_B, T_C, W2p, W3p, pe_b2, pe_b3,
                                  zjA, zkA, ggeom, pagg);
    k_out<<<128, 256, 0, stream>>>(pagg, op_W1, op_b1, op_W2, op_b2, out);
}

// Round 3
// 523.766 us; speedup vs baseline: 1.1375x; 1.0788x over previous
//
#include <hip/hip_runtime.h>
#include <hip/hip_bf16.h>
#include <stdint.h>

// ---------------------------------------------------------------------------
// AbsorberPathAggregator — MI355X (gfx950)  v3
// Sizes: B=32, N=64, H=128, RBF=32, GH=256, SC=64, OUT=256, PMAX=256, NE=64
// v3: fix register spilling in k_pe (was the 650MB phantom traffic):
//     - no W3 fragment preload (stream from L2-hot global in GEMM2)
//     - launch_bounds(256,1) so compiler allocates ~200 VGPR spill-free
//     - X2 overlays X1 (single 32KB LDS buffer)
// ---------------------------------------------------------------------------

#define CUTOFF_F 6.0f

typedef __bf16 bf16x8_t __attribute__((ext_vector_type(8)));
typedef float  f32x4_t  __attribute__((ext_vector_type(4)));

union FragU { bf16x8_t v; uint32_t u[4]; uint2 d2[2]; uint4 d4; };

// fast silu: x * rcp(1 + exp2(-x*log2e))
__device__ __forceinline__ float silu_f(float x){
    float e = __builtin_amdgcn_exp2f(x * -1.44269504088896f);
    return x * __builtin_amdgcn_rcpf(1.0f + e);
}

__device__ __forceinline__ uint16_t f2bf(float a){
    union { __hip_bfloat16 h; uint16_t u; } c; c.h = __float2bfloat16(a); return c.u;
}
__device__ __forceinline__ uint32_t pk2(float a, float b){
    union { __hip_bfloat162 h; uint32_t u; } c;
    c.h = __float22bfloat162_rn(make_float2(a, b));
    return c.u;
}
__device__ __forceinline__ void frag_lds(FragU& f, const char* base, uint32_t b0, uint32_t b1){
    f.d2[0] = *(const uint2*)(base + b0);
    f.d2[1] = *(const uint2*)(base + b1);
}
__device__ __forceinline__ void frag_gp(FragU& f, const uint16_t* p){
    f.d4 = *(const uint4*)(p);
}

// ---------------------------------------------------------------------------
// K0a: T_A[101][256], T_B[101][256], T_C[64][256] (f32)
// ---------------------------------------------------------------------------
__global__ void k_tables(const float* __restrict__ z_emb, const float* __restrict__ e_feat,
                         const float* __restrict__ pe_W1, const float* __restrict__ pe_b1,
                         float* __restrict__ T_A, float* __restrict__ T_B, float* __restrict__ T_C){
    int row = blockIdx.x; int c = threadIdx.x;
    if (row < 101){
        const float* e = z_emb + row*32;
        float s = 0.f;
        #pragma unroll
        for (int d = 0; d < 32; d++) s += e[d] * pe_W1[d*256 + c];
        T_A[row*256 + c] = s;
    } else if (row < 202){
        const float* e = z_emb + (row-101)*32;
        float s = 0.f;
        #pragma unroll
        for (int d = 0; d < 32; d++) s += e[d] * pe_W1[(32+d)*256 + c];
        T_B[(row-101)*256 + c] = s;
    } else {
        int n = row - 202;
        const float* e = e_feat + n*32;
        float s = pe_b1[c];
        #pragma unroll
        for (int d = 0; d < 32; d++) s += e[d] * pe_W1[(64+d)*256 + c];
        T_C[n*256 + c] = s;
    }
}

// ---------------------------------------------------------------------------
// K0b: weight prep -> bf16 packed fragment-contiguous layouts.
//   packed p = q*8 + j  <->  k = kt*32 + 4q + (j&3) + 16*(j>>2)
// ---------------------------------------------------------------------------
__global__ void k_prep(const float* __restrict__ pe_W2, const float* __restrict__ pe_W3,
                       const float* __restrict__ gm_W1, const float* __restrict__ gm_W2,
                       const float* __restrict__ gm_W3,
                       uint16_t* __restrict__ W2p, uint16_t* __restrict__ W3p,
                       uint16_t* __restrict__ gW1p, uint16_t* __restrict__ gW2p,
                       uint16_t* __restrict__ gW3p){
    int idx = blockIdx.x*256 + threadIdx.x;   // 262144 total
    if (idx < 65536){                                   // W2p [256c][256]
        int d = idx; int c = d >> 8; int r = d & 255;
        int kt = r >> 5, t = r & 31, q = t >> 3, j = t & 7;
        int k = kt*32 + 4*q + (j&3) + ((j>>2)<<4);
        W2p[d] = f2bf(pe_W2[k*256 + c]);
    } else if (idx < 81920){                            // W3p [64s][256]
        int d = idx - 65536; int s = d >> 8; int r = d & 255;
        int kt = r >> 5, t = r & 31, q = t >> 3, j = t & 7;
        int k = kt*32 + 4*q + (j&3) + ((j>>2)<<4);
        W3p[d] = f2bf(pe_W3[k*64 + s]);
    } else if (idx < 180224){                           // gW1p [256c][384], zero-pad k>=353
        int d = idx - 81920; int c = d / 384; int r = d - c*384;
        int kt = r >> 5, t = r & 31, q = t >> 3, j = t & 7;
        int k = kt*32 + 4*q + (j&3) + ((j>>2)<<4);
        float v = (k < 353) ? gm_W1[k*256 + c] : 0.0f;
        gW1p[d] = f2bf(v);
    } else if (idx < 245760){                           // gW2p [256c][256]
        int d = idx - 180224; int c = d >> 8; int r = d & 255;
        int kt = r >> 5, t = r & 31, q = t >> 3, j = t & 7;
        int k = kt*32 + 4*q + (j&3) + ((j>>2)<<4);
        gW2p[d] = f2bf(gm_W2[k*256 + c]);
    } else {                                            // gW3p [64s][256]
        int d = idx - 245760; int s = d >> 8; int r = d & 255;
        int kt = r >> 5, t = r & 31, q = t >> 3, j = t & 7;
        int k = kt*32 + 4*q + (j&3) + ((j>>2)<<4);
        gW3p[d] = f2bf(gm_W3[k*64 + s]);
    }
}

// ---------------------------------------------------------------------------
// K1: pair selection per batch (1 wave). First PMAX valid (j<k) pairs, lex order.
// ---------------------------------------------------------------------------
__global__ void k_pairs(const float* __restrict__ pos, const int* __restrict__ mask,
                        const int* __restrict__ zin, const int* __restrict__ aidx,
                        int* __restrict__ jA, int* __restrict__ kA,
                        int* __restrict__ zjA, int* __restrict__ zkA,
                        float* __restrict__ pmask, float* __restrict__ pgeo){
    const int b = blockIdx.x;
    const int j = threadIdx.x;
    const int ai = aidx[0];
    __shared__ float sx[64], sy[64], sz[64], sr[64];

    bool okp = true;
    #pragma unroll
    for (int i = 0; i < 2; i++){
        int v = mask[j + 64*i];
        okp = okp && (v == 0 || v == 1);
    }
    const bool isI32 = (__all(okp) != 0);

    float p0x = pos[(b*64+ai)*3+0];
    float p0y = pos[(b*64+ai)*3+1];
    float p0z = pos[(b*64+ai)*3+2];
    float x  = pos[(b*64+j)*3+0];
    float y  = pos[(b*64+j)*3+1];
    float zc = pos[(b*64+j)*3+2];
    float dx = x-p0x, dy = y-p0y, dz = zc-p0z;
    float r = sqrtf(dx*dx + dy*dy + dz*dz + 1e-12f);
    bool mv = isI32 ? (mask[b*64+j] != 0) : (((const unsigned char*)mask)[b*64+j] != 0);
    bool valid = mv && (j != ai) && (r <= CUTOFF_F);
    sx[j]=x; sy[j]=y; sz[j]=zc; sr[j]=r;
    unsigned long long vm = __ballot(valid);
    __syncthreads();

    int z0 = zin[b*64 + 0];
    for (int s = j; s < 256; s += 64){
        int slot = b*256 + s;
        jA[slot]=0; kA[slot]=0; zjA[slot]=z0; zkA[slot]=z0;
        pmask[slot]=0.0f;
        pgeo[slot*4+0]=0.0f; pgeo[slot*4+1]=0.0f; pgeo[slot*4+2]=0.0f; pgeo[slot*4+3]=0.0f;
    }
    __syncthreads();

    int prefix = 0;
    for (int i = 0; i < 63; i++){
        if (i < j && ((vm>>i)&1ull)) prefix += __popcll(vm >> (i+1));
    }
    if (valid){
        int rank = prefix;
        for (int k = j+1; k < 64; k++){
            if ((vm>>k)&1ull){
                if (rank < 256){
                    int slot = b*256 + rank;
                    jA[slot]=j; kA[slot]=k;
                    zjA[slot]=zin[b*64+j]; zkA[slot]=zin[b*64+k];
                    pmask[slot]=1.0f;
                    float vkx=sx[k]-p0x, vky=sy[k]-p0y, vkz=sz[k]-p0z;
                    float jkx=sx[k]-x,   jky=sy[k]-y,   jkz=sz[k]-zc;
                    float rjk = sqrtf(jkx*jkx + jky*jky + jkz*jkz + 1e-12f);
                    float r0k = sr[k];
                    float inj = 1.0f/fmaxf(r,   1e-8f);
                    float ink = 1.0f/fmaxf(r0k, 1e-8f);
                    float cs = (dx*vkx + dy*vky + dz*vkz) * inj * ink;
                    cs = fminf(fmaxf(cs, -1.0f), 1.0f);
                    pgeo[slot*4+0]=r; pgeo[slot*4+1]=r0k; pgeo[slot*4+2]=rjk; pgeo[slot*4+3]=cs;
                }
                rank++;
            }
        }
    }
}

// ---------------------------------------------------------------------------
// K2: geom MLP (353->256->256->64). 16 pair-rows per block, 512 blocks.
// ---------------------------------------------------------------------------
__launch_bounds__(256, 1)
__global__ void k_geom(const float* __restrict__ h, const int* __restrict__ jA, const int* __restrict__ kA,
                       const float* __restrict__ pmask, const float* __restrict__ pgeo,
                       const uint16_t* __restrict__ gW1p, const uint16_t* __restrict__ gW2p,
                       const uint16_t* __restrict__ gW3p,
                       const float* __restrict__ gb1, const float* __restrict__ gb2,
                       const float* __restrict__ gb3, float* __restrict__ ggeom){
    __shared__ __align__(16) char X0[16*768];   // 12288 B: features / later X2 [16][512B]
    __shared__ __align__(16) char X1[16*512];   // 8192 B
    const int b = blockIdx.x >> 4, pc = blockIdx.x & 15;
    const int tid = threadIdx.x;
    const int w = tid >> 6, l = tid & 63, l15 = l & 15, l4 = l >> 4;
    const int pbase = b*256 + pc*16;
    const float GAMMA = 26.694444444444443f;    // (31/6)^2
    const float STEP  = 0.19354838709677419f;   // 6/31

    // ---- build X0 [16 rows][384 cols] bf16 (swizzled) ----
    for (int e = tid; e < 16*96; e += 256){
        int row = e / 96;
        int q = e - row*96;
        int slot = pbase + row;
        float f0=0.f, f1=0.f, f2=0.f, f3=0.f;
        if (q < 64){
            int idxa = (q < 32) ? jA[slot] : kA[slot];
            int koff = (q < 32) ? (q*4) : (q*4 - 128);
            const float* hp = h + ((b*64 + idxa)*128 + koff);
            f0=hp[0]; f1=hp[1]; f2=hp[2]; f3=hp[3];
        } else if (q < 88){
            int kk = q*4 - 256;
            int reg = kk >> 5;
            int t0 = kk & 31;
            float rr = fminf(pgeo[slot*4 + reg], CUTOFF_F);
            float d0 = rr - (float)(t0+0)*STEP; f0 = __builtin_amdgcn_exp2f(-GAMMA*d0*d0*1.44269504088896f);
            float d1 = rr - (float)(t0+1)*STEP; f1 = __builtin_amdgcn_exp2f(-GAMMA*d1*d1*1.44269504088896f);
            float d2 = rr - (float)(t0+2)*STEP; f2 = __builtin_amdgcn_exp2f(-GAMMA*d2*d2*1.44269504088896f);
            float d3 = rr - (float)(t0+3)*STEP; f3 = __builtin_amdgcn_exp2f(-GAMMA*d3*d3*1.44269504088896f);
        } else if (q == 88){
            f0 = pgeo[slot*4+3];    // cosang; k=353..383 zero pad
        }
        uint32_t byte = (uint32_t)row*768u + (((uint32_t)(8*q)) ^ (((uint32_t)(row&7))<<4));
        *(uint2*)(X0 + byte) = make_uint2(pk2(f0,f1), pk2(f2,f3));
    }
    __syncthreads();

    // ---- GEMM1: [16 x 256], K=384 ----
    f32x4_t a1[4];
    #pragma unroll
    for (int nt=0; nt<4; nt++){ a1[nt][0]=0;a1[nt][1]=0;a1[nt][2]=0;a1[nt][3]=0; }
    #pragma unroll 3
    for (int kt=0; kt<12; kt++){
        int k0 = 4*l4 + 32*kt;
        int row = l15;
        uint32_t sw = ((uint32_t)(row&7))<<4;
        FragU A;
        frag_lds(A, X0, (uint32_t)row*768u + (((uint32_t)(2*k0))^sw),
                        (uint32_t)row*768u + (((uint32_t)(2*k0+32))^sw));
        FragU Bf[4];
        #pragma unroll
        for (int nt=0; nt<4; nt++)
            frag_gp(Bf[nt], gW1p + (64*w + 16*nt + l15)*384 + kt*32 + l4*8);
        __builtin_amdgcn_s_setprio(1);
        #pragma unroll
        for (int nt=0; nt<4; nt++)
            a1[nt] = __builtin_amdgcn_mfma_f32_16x16x32_bf16(A.v, Bf[nt].v, a1[nt], 0,0,0);
        __builtin_amdgcn_s_setprio(0);
    }
    #pragma unroll
    for (int nt=0; nt<4; nt++){
        int c = 64*w + 16*nt + l15;
        float bias = gb1[c];
        #pragma unroll
        for (int r=0; r<4; r++){
            int m = 4*l4 + r;
            float v = silu_f(a1[nt][r] + bias);
            uint32_t byte = (uint32_t)m*512u + (((uint32_t)(2*c)) ^ (((uint32_t)(m&7))<<4));
            *(uint16_t*)(X1 + byte) = f2bf(v);
        }
    }
    __syncthreads();

    // ---- GEMM2: [16 x 256], K=256 ----
    f32x4_t a2[4];
    #pragma unroll
    for (int nt=0; nt<4; nt++){ a2[nt][0]=0;a2[nt][1]=0;a2[nt][2]=0;a2[nt][3]=0; }
    #pragma unroll 2
    for (int kt=0; kt<8; kt++){
        int k0 = 4*l4 + 32*kt;
        int row = l15;
        uint32_t sw = ((uint32_t)(row&7))<<4;
        FragU A;
        frag_lds(A, X1, (uint32_t)row*512u + (((uint32_t)(2*k0))^sw),
                        (uint32_t)row*512u + (((uint32_t)(2*k0+32))^sw));
        FragU Bf[4];
        #pragma unroll
        for (int nt=0; nt<4; nt++)
            frag_gp(Bf[nt], gW2p + (64*w + 16*nt + l15)*256 + kt*32 + l4*8);
        __builtin_amdgcn_s_setprio(1);
        #pragma unroll
        for (int nt=0; nt<4; nt++)
            a2[nt] = __builtin_amdgcn_mfma_f32_16x16x32_bf16(A.v, Bf[nt].v, a2[nt], 0,0,0);
        __builtin_amdgcn_s_setprio(0);
    }
    #pragma unroll
    for (int nt=0; nt<4; nt++){
        int c = 64*w + 16*nt + l15;
        float bias = gb2[c];
        #pragma unroll
        for (int r=0; r<4; r++){
            int m = 4*l4 + r;
            float v = silu_f(a2[nt][r] + bias);
            uint32_t byte = (uint32_t)m*512u + (((uint32_t)(2*c)) ^ (((uint32_t)(m&7))<<4));
            *(uint16_t*)(X0 + byte) = f2bf(v);   // X2 lives in X0, stride 512B
        }
    }
    __syncthreads();

    // ---- GEMM3: [16 x 64], K=256; wave w owns cols 16w..16w+15 ----
    f32x4_t a3;
    a3[0]=0;a3[1]=0;a3[2]=0;a3[3]=0;
    int s = 16*w + l15;
    #pragma unroll 2
    for (int kt=0; kt<8; kt++){
        int k0 = 4*l4 + 32*kt;
        FragU Bf; frag_gp(Bf, gW3p + s*256 + kt*32 + l4*8);
        int row = l15;
        uint32_t sw = ((uint32_t)(row&7))<<4;
        FragU A;
        frag_lds(A, X0, (uint32_t)row*512u + (((uint32_t)(2*k0))^sw),
                        (uint32_t)row*512u + (((uint32_t)(2*k0+32))^sw));
        a3 = __builtin_amdgcn_mfma_f32_16x16x32_bf16(A.v, Bf.v, a3, 0,0,0);
    }
    float bias3 = gb3[s];
    #pragma unroll
    for (int r=0; r<4; r++){
        int prow = 4*l4 + r;
        int slot = pbase + prow;
        ggeom[slot*64 + s] = (a3[r] + bias3) * pmask[slot];
    }
}

// ---------------------------------------------------------------------------
// K3: main pe-MLP. 512 blocks = (batch b, chunk of 16 pairs). 32 KiB LDS
// (X2 overlays X1). W2/W3 B-frags streamed from packed L2 globals (1x16B).
// Per pair: X1=silu(T_A[zj]+T_B[zk]+T_C[n]) -> GEMM1(64x256x256) -> silu ->
// GEMM2(64x64x256) -> *g_geom, reg-accumulate. Partials to pagg (no atomics).
// ---------------------------------------------------------------------------
__launch_bounds__(256, 1)
__global__ void k_pe(const float* __restrict__ T_A, const float* __restrict__ T_B,
                     const float* __restrict__ T_C,
                     const uint16_t* __restrict__ W2p, const uint16_t* __restrict__ W3p,
                     const float* __restrict__ b2, const float* __restrict__ b3,
                     const int* __restrict__ zjA, const int* __restrict__ zkA,
                     const float* __restrict__ ggeom, float* __restrict__ pagg){
    __shared__ __align__(16) char Xs[64*512];   // 32768 B: X1, then X2 overlay
    const int b = blockIdx.x >> 4, pc = blockIdx.x & 15;
    const int tid = threadIdx.x;
    const int w = tid >> 6, l = tid & 63, l15 = l & 15, l4 = l >> 4;

    float b2v[4], b3v[4];
    #pragma unroll
    for (int nt=0; nt<4; nt++){
        b2v[nt] = b2[64*w + 16*nt + l15];
        b3v[nt] = b3[16*nt + l15];
    }
    f32x4_t pacc[4];
    #pragma unroll
    for (int nt=0; nt<4; nt++){ pacc[nt][0]=0;pacc[nt][1]=0;pacc[nt][2]=0;pacc[nt][3]=0; }

    const int kb = tid & 63, nset = tid >> 6;   // X1-build roles
    const int k4 = kb*4;

    for (int pi = 0; pi < 16; pi++){
        const int slot = b*256 + pc*16 + pi;
        // ---- build X1 = silu(T_A[zj]+T_B[zk]+T_C[n]) -> Xs (bf16, swizzled) ----
        {
            int zj = zjA[slot], zk = zkA[slot];
            float4 ta = *(const float4*)(T_A + zj*256 + k4);
            float4 tb = *(const float4*)(T_B + zk*256 + k4);
            float bx = ta.x+tb.x, by = ta.y+tb.y, bz = ta.z+tb.z, bw = ta.w+tb.w;
            #pragma unroll
            for (int i = 0; i < 16; i++){
                int n = nset*16 + i;
                float4 tc = *(const float4*)(T_C + n*256 + k4);
                float v0 = silu_f(bx+tc.x), v1 = silu_f(by+tc.y);
                float v2 = silu_f(bz+tc.z), v3 = silu_f(bw+tc.w);
                uint32_t byte = (uint32_t)n*512u + (((uint32_t)(8*kb)) ^ (((uint32_t)(i&7))<<4));
                *(uint2*)(Xs + byte) = make_uint2(pk2(v0,v1), pk2(v2,v3));
            }
        }
        __syncthreads();   // bar1: X1 ready
        // ---- GEMM1: [64 x 256], K=256; wave w owns cols 64w..64w+63 ----
        f32x4_t a1[4][4];
        #pragma unroll
        for (int mt=0; mt<4; mt++)
            #pragma unroll
            for (int nt=0; nt<4; nt++){ a1[mt][nt][0]=0;a1[mt][nt][1]=0;a1[mt][nt][2]=0;a1[mt][nt][3]=0; }
        #pragma unroll 2
        for (int kt=0; kt<8; kt++){
            int k0 = 4*l4 + 32*kt;
            FragU Bf[4];
            #pragma unroll
            for (int nt=0; nt<4; nt++)
                frag_gp(Bf[nt], W2p + (64*w + 16*nt + l15)*256 + kt*32 + l4*8);
            FragU A[4];
            #pragma unroll
            for (int mt=0; mt<4; mt++){
                int row = 16*mt + l15;
                uint32_t sw = ((uint32_t)(row&7))<<4;
                frag_lds(A[mt], Xs, (uint32_t)row*512u + (((uint32_t)(2*k0))^sw),
                                    (uint32_t)row*512u + (((uint32_t)(2*k0+32))^sw));
            }
            __builtin_amdgcn_s_setprio(1);
            #pragma unroll
            for (int nt=0; nt<4; nt++)
                #pragma unroll
                for (int mt=0; mt<4; mt++)
                    a1[mt][nt] = __builtin_amdgcn_mfma_f32_16x16x32_bf16(A[mt].v, Bf[nt].v, a1[mt][nt], 0,0,0);
            __builtin_amdgcn_s_setprio(0);
        }
        __syncthreads();   // bar2: all waves done reading X1
        // ---- silu + store X2 (bf16) into Xs (overlay) ----
        #pragma unroll
        for (int nt=0; nt<4; nt++){
            int c = 64*w + 16*nt + l15;
            #pragma unroll
            for (int mt=0; mt<4; mt++)
                #pragma unroll
                for (int r=0; r<4; r++){
                    int m = 16*mt + 4*l4 + r;
                    float v = silu_f(a1[mt][nt][r] + b2v[nt]);
                    uint32_t byte = (uint32_t)m*512u + (((uint32_t)(2*c)) ^ (((uint32_t)(m&7))<<4));
                    *(uint16_t*)(Xs + byte) = f2bf(v);
                }
        }
        __syncthreads();   // bar3: X2 ready
        // ---- GEMM2: [64 x 64], K=256; wave w owns rows 16w..16w+15 ----
        f32x4_t a2[4];
        #pragma unroll
        for (int nt=0; nt<4; nt++){ a2[nt][0]=0;a2[nt][1]=0;a2[nt][2]=0;a2[nt][3]=0; }
        #pragma unroll 2
        for (int kt=0; kt<8; kt++){
            int k0 = 4*l4 + 32*kt;
            FragU Wf[4];
            #pragma unroll
            for (int nt=0; nt<4; nt++)
                frag_gp(Wf[nt], W3p + (16*nt + l15)*256 + kt*32 + l4*8);
            int row = 16*w + l15;
            uint32_t sw = ((uint32_t)(row&7))<<4;
            FragU A;
            frag_lds(A, Xs, (uint32_t)row*512u + (((uint32_t)(2*k0))^sw),
                            (uint32_t)row*512u + (((uint32_t)(2*k0+32))^sw));
            __builtin_amdgcn_s_setprio(1);
            #pragma unroll
            for (int nt=0; nt<4; nt++)
                a2[nt] = __builtin_amdgcn_mfma_f32_16x16x32_bf16(A.v, Wf[nt].v, a2[nt], 0,0,0);
            __builtin_amdgcn_s_setprio(0);
        }
        // ---- fuse: g_elem * g_geom, accumulate over pairs in registers ----
        #pragma unroll
        for (int nt=0; nt<4; nt++){
            float gg = ggeom[slot*64 + 16*nt + l15];
            #pragma unroll
            for (int r=0; r<4; r++)
                pacc[nt][r] += (a2[nt][r] + b3v[nt]) * gg;
        }
        __syncthreads();   // bar4: done reading X2 before next X1 build
    }
    // ---- commit partials (no atomics): pagg[chunk][n][s] ----
    const int chunk = b*16 + pc;
    #pragma unroll
    for (int nt=0; nt<4; nt++)
        #pragma unroll
        for (int r=0; r<4; r++){
            int n = 16*w + 4*l4 + r;
            int s = 16*nt + l15;
            pagg[(chunk*64 + n)*64 + s] = pacc[nt][r];
        }
}

// ---------------------------------------------------------------------------
// K4: agg = sum over 16 chunks; out = silu(agg @ op_W1 + b1) @ op_W2 + b2
// ---------------------------------------------------------------------------
__global__ void k_out(const float* __restrict__ pagg, const float* __restrict__ W1,
                      const float* __restrict__ bb1, const float* __restrict__ W2,
                      const float* __restrict__ bb2, float* __restrict__ out){
    __shared__ float sag[16][64];
    __shared__ float shid[16][256];
    const int row0 = blockIdx.x * 16;   // rows of [B*NE = 2048]
    const int tid = threadIdx.x;
    const int bb = row0 >> 6;           // 16-row block stays within one batch
    for (int i = tid; i < 16*64; i += 256){
        int row = row0 + (i >> 6);
        int nn = row & 63;
        int k = i & 63;
        float acc = 0.f;
        #pragma unroll
        for (int pcc = 0; pcc < 16; pcc++)
            acc += pagg[((bb*16 + pcc)*64 + nn)*64 + k];
        sag[i>>6][k] = acc;
    }
    __syncthreads();
    float a[16];
    #pragma unroll
    for (int i=0;i<16;i++) a[i] = bb1[tid];
    for (int k=0;k<64;k++){
        float wv = W1[k*256 + tid];
        #pragma unroll
        for (int i=0;i<16;i++) a[i] += sag[i][k]*wv;
    }
    #pragma unroll
    for (int i=0;i<16;i++) shid[i][tid] = silu_f(a[i]);
    __syncthreads();
    float o[16];
    #pragma unroll
    for (int i=0;i<16;i++) o[i] = bb2[tid];
    for (int c=0;c<256;c++){
        float wv = W2[c*256 + tid];
        #pragma unroll
        for (int i=0;i<16;i++) o[i] += shid[i][c]*wv;
    }
    #pragma unroll
    for (int i=0;i<16;i++) out[(row0+i)*256 + tid] = o[i];
}

// ---------------------------------------------------------------------------
extern "C" void kernel_launch(void* const* d_in, const int* in_sizes, int n_in,
                              void* d_out, int out_size, void* d_ws, size_t ws_size,
                              hipStream_t stream){
    const float* h      = (const float*)d_in[0];
    const int*   z      = (const int*)  d_in[1];
    const float* pos    = (const float*)d_in[2];
    const int*   mask   = (const int*)  d_in[3];
    const float* e_feat = (const float*)d_in[4];
    const float* z_emb  = (const float*)d_in[5];
    const float* gm_W1  = (const float*)d_in[6];
    const float* gm_b1  = (const float*)d_in[7];
    const float* gm_W2  = (const float*)d_in[8];
    const float* gm_b2  = (const float*)d_in[9];
    const float* gm_W3  = (const float*)d_in[10];
    const float* gm_b3  = (const float*)d_in[11];
    const float* pe_W1  = (const float*)d_in[12];
    const float* pe_b1  = (const float*)d_in[13];
    const float* pe_W2  = (const float*)d_in[14];
    const float* pe_b2  = (const float*)d_in[15];
    const float* pe_W3  = (const float*)d_in[16];
    const float* pe_b3  = (const float*)d_in[17];
    const float* op_W1  = (const float*)d_in[18];
    const float* op_b1  = (const float*)d_in[19];
    const float* op_W2  = (const float*)d_in[20];
    const float* op_b2  = (const float*)d_in[21];
    const int*   aidx   = (const int*)  d_in[22];
    float* out = (float*)d_out;
    char* ws = (char*)d_ws;

    // workspace layout (bytes, 16B-aligned)
    float*    T_A   = (float*)   (ws + 0);        // 103424
    float*    T_B   = (float*)   (ws + 103424);   // 103424
    float*    T_C   = (float*)   (ws + 206848);   // 65536
    uint16_t* W2p   = (uint16_t*)(ws + 272384);   // 131072
    uint16_t* W3p   = (uint16_t*)(ws + 403456);   // 32768
    uint16_t* gW1p  = (uint16_t*)(ws + 436224);   // 196608
    uint16_t* gW2p  = (uint16_t*)(ws + 632832);   // 131072
    uint16_t* gW3p  = (uint16_t*)(ws + 763904);   // 32768
    int*      jA    = (int*)     (ws + 796672);   // 32768
    int*      kA    = (int*)     (ws + 829440);
    int*      zjA   = (int*)     (ws + 862208);
    int*      zkA   = (int*)     (ws + 894976);
    float*    pmask = (float*)   (ws + 927744);
    float*    pgeo  = (float*)   (ws + 960512);   // 131072
    float*    ggeom = (float*)   (ws + 1091584);  // 2097152
    float*    pagg  = (float*)   (ws + 3188736);  // 8388608 (512 chunks x 64 x 64 f32)

    k_tables<<<266, 256, 0, stream>>>(z_emb, e_feat, pe_W1, pe_b1, T_A, T_B, T_C);
    k_prep<<<1024, 256, 0, stream>>>(pe_W2, pe_W3, gm_W1, gm_W2, gm_W3, W2p, W3p, gW1p, gW2p, gW3p);
    k_pairs<<<32, 64, 0, stream>>>(pos, mask, z, aidx, jA, kA, zjA, zkA, pmask, pgeo);
    k_geom<<<512, 256, 0, stream>>>(h, jA, kA, pmask, pgeo, gW1p, gW2p, gW3p,
                                    gm_b1, gm_b2, gm_b3, ggeom);
    k_pe<<<512, 256, 0, stream>>>(T_A, T_B, T_C, W2p, W3p, pe_b2, pe_b3,
                                  zjA, zkA, ggeom, pagg);
    k_out<<<128, 256, 0, stream>>>(pagg, op_W1, op_b1, op_W2, op_b2, out);
}

// Round 4
// 402.803 us; speedup vs baseline: 1.4792x; 1.3003x over previous
//
#include <hip/hip_runtime.h>
#include <hip/hip_bf16.h>
#include <stdint.h>

// ---------------------------------------------------------------------------
// AbsorberPathAggregator — MI355X (gfx950)  v4
// v4: k_pe restructured to 8-wave blocks (512 thr), 256 blocks = 1/CU, 1 round.
//     Per-wave GEMM1 tile 32 cols (a1[4][2]); GEMM2 split-K across wave pairs.
//     Guarantees 2 waves/SIMD co-residency (was 1 — unified VGPR+AGPR limit).
// ---------------------------------------------------------------------------

#define CUTOFF_F 6.0f

typedef __bf16 bf16x8_t __attribute__((ext_vector_type(8)));
typedef float  f32x4_t  __attribute__((ext_vector_type(4)));

union FragU { bf16x8_t v; uint32_t u[4]; uint2 d2[2]; uint4 d4; };

// fast silu: x * rcp(1 + exp2(-x*log2e))
__device__ __forceinline__ float silu_f(float x){
    float e = __builtin_amdgcn_exp2f(x * -1.44269504088896f);
    return x * __builtin_amdgcn_rcpf(1.0f + e);
}

__device__ __forceinline__ uint16_t f2bf(float a){
    union { __hip_bfloat16 h; uint16_t u; } c; c.h = __float2bfloat16(a); return c.u;
}
__device__ __forceinline__ uint32_t pk2(float a, float b){
    union { __hip_bfloat162 h; uint32_t u; } c;
    c.h = __float22bfloat162_rn(make_float2(a, b));
    return c.u;
}
__device__ __forceinline__ void frag_lds(FragU& f, const char* base, uint32_t b0, uint32_t b1){
    f.d2[0] = *(const uint2*)(base + b0);
    f.d2[1] = *(const uint2*)(base + b1);
}
__device__ __forceinline__ void frag_gp(FragU& f, const uint16_t* p){
    f.d4 = *(const uint4*)(p);
}

// ---------------------------------------------------------------------------
// K0a: T_A[101][256], T_B[101][256], T_C[64][256] (f32)
// ---------------------------------------------------------------------------
__global__ void k_tables(const float* __restrict__ z_emb, const float* __restrict__ e_feat,
                         const float* __restrict__ pe_W1, const float* __restrict__ pe_b1,
                         float* __restrict__ T_A, float* __restrict__ T_B, float* __restrict__ T_C){
    int row = blockIdx.x; int c = threadIdx.x;
    if (row < 101){
        const float* e = z_emb + row*32;
        float s = 0.f;
        #pragma unroll
        for (int d = 0; d < 32; d++) s += e[d] * pe_W1[d*256 + c];
        T_A[row*256 + c] = s;
    } else if (row < 202){
        const float* e = z_emb + (row-101)*32;
        float s = 0.f;
        #pragma unroll
        for (int d = 0; d < 32; d++) s += e[d] * pe_W1[(32+d)*256 + c];
        T_B[(row-101)*256 + c] = s;
    } else {
        int n = row - 202;
        const float* e = e_feat + n*32;
        float s = pe_b1[c];
        #pragma unroll
        for (int d = 0; d < 32; d++) s += e[d] * pe_W1[(64+d)*256 + c];
        T_C[n*256 + c] = s;
    }
}

// ---------------------------------------------------------------------------
// K0b: weight prep -> bf16 packed fragment-contiguous layouts.
//   packed p = q*8 + j  <->  k = kt*32 + 4q + (j&3) + 16*(j>>2)
// ---------------------------------------------------------------------------
__global__ void k_prep(const float* __restrict__ pe_W2, const float* __restrict__ pe_W3,
                       const float* __restrict__ gm_W1, const float* __restrict__ gm_W2,
                       const float* __restrict__ gm_W3,
                       uint16_t* __restrict__ W2p, uint16_t* __restrict__ W3p,
                       uint16_t* __restrict__ gW1p, uint16_t* __restrict__ gW2p,
                       uint16_t* __restrict__ gW3p){
    int idx = blockIdx.x*256 + threadIdx.x;   // 262144 total
    if (idx < 65536){                                   // W2p [256c][256]
        int d = idx; int c = d >> 8; int r = d & 255;
        int kt = r >> 5, t = r & 31, q = t >> 3, j = t & 7;
        int k = kt*32 + 4*q + (j&3) + ((j>>2)<<4);
        W2p[d] = f2bf(pe_W2[k*256 + c]);
    } else if (idx < 81920){                            // W3p [64s][256]
        int d = idx - 65536; int s = d >> 8; int r = d & 255;
        int kt = r >> 5, t = r & 31, q = t >> 3, j = t & 7;
        int k = kt*32 + 4*q + (j&3) + ((j>>2)<<4);
        W3p[d] = f2bf(pe_W3[k*64 + s]);
    } else if (idx < 180224){                           // gW1p [256c][384], zero-pad k>=353
        int d = idx - 81920; int c = d / 384; int r = d - c*384;
        int kt = r >> 5, t = r & 31, q = t >> 3, j = t & 7;
        int k = kt*32 + 4*q + (j&3) + ((j>>2)<<4);
        float v = (k < 353) ? gm_W1[k*256 + c] : 0.0f;
        gW1p[d] = f2bf(v);
    } else if (idx < 245760){                           // gW2p [256c][256]
        int d = idx - 180224; int c = d >> 8; int r = d & 255;
        int kt = r >> 5, t = r & 31, q = t >> 3, j = t & 7;
        int k = kt*32 + 4*q + (j&3) + ((j>>2)<<4);
        gW2p[d] = f2bf(gm_W2[k*256 + c]);
    } else {                                            // gW3p [64s][256]
        int d = idx - 245760; int s = d >> 8; int r = d & 255;
        int kt = r >> 5, t = r & 31, q = t >> 3, j = t & 7;
        int k = kt*32 + 4*q + (j&3) + ((j>>2)<<4);
        gW3p[d] = f2bf(gm_W3[k*64 + s]);
    }
}

// ---------------------------------------------------------------------------
// K1: pair selection per batch (1 wave). First PMAX valid (j<k) pairs, lex order.
// ---------------------------------------------------------------------------
__global__ void k_pairs(const float* __restrict__ pos, const int* __restrict__ mask,
                        const int* __restrict__ zin, const int* __restrict__ aidx,
                        int* __restrict__ jA, int* __restrict__ kA,
                        int* __restrict__ zjA, int* __restrict__ zkA,
                        float* __restrict__ pmask, float* __restrict__ pgeo){
    const int b = blockIdx.x;
    const int j = threadIdx.x;
    const int ai = aidx[0];
    __shared__ float sx[64], sy[64], sz[64], sr[64];

    bool okp = true;
    #pragma unroll
    for (int i = 0; i < 2; i++){
        int v = mask[j + 64*i];
        okp = okp && (v == 0 || v == 1);
    }
    const bool isI32 = (__all(okp) != 0);

    float p0x = pos[(b*64+ai)*3+0];
    float p0y = pos[(b*64+ai)*3+1];
    float p0z = pos[(b*64+ai)*3+2];
    float x  = pos[(b*64+j)*3+0];
    float y  = pos[(b*64+j)*3+1];
    float zc = pos[(b*64+j)*3+2];
    float dx = x-p0x, dy = y-p0y, dz = zc-p0z;
    float r = sqrtf(dx*dx + dy*dy + dz*dz + 1e-12f);
    bool mv = isI32 ? (mask[b*64+j] != 0) : (((const unsigned char*)mask)[b*64+j] != 0);
    bool valid = mv && (j != ai) && (r <= CUTOFF_F);
    sx[j]=x; sy[j]=y; sz[j]=zc; sr[j]=r;
    unsigned long long vm = __ballot(valid);
    __syncthreads();

    int z0 = zin[b*64 + 0];
    for (int s = j; s < 256; s += 64){
        int slot = b*256 + s;
        jA[slot]=0; kA[slot]=0; zjA[slot]=z0; zkA[slot]=z0;
        pmask[slot]=0.0f;
        pgeo[slot*4+0]=0.0f; pgeo[slot*4+1]=0.0f; pgeo[slot*4+2]=0.0f; pgeo[slot*4+3]=0.0f;
    }
    __syncthreads();

    int prefix = 0;
    for (int i = 0; i < 63; i++){
        if (i < j && ((vm>>i)&1ull)) prefix += __popcll(vm >> (i+1));
    }
    if (valid){
        int rank = prefix;
        for (int k = j+1; k < 64; k++){
            if ((vm>>k)&1ull){
                if (rank < 256){
                    int slot = b*256 + rank;
                    jA[slot]=j; kA[slot]=k;
                    zjA[slot]=zin[b*64+j]; zkA[slot]=zin[b*64+k];
                    pmask[slot]=1.0f;
                    float vkx=sx[k]-p0x, vky=sy[k]-p0y, vkz=sz[k]-p0z;
                    float jkx=sx[k]-x,   jky=sy[k]-y,   jkz=sz[k]-zc;
                    float rjk = sqrtf(jkx*jkx + jky*jky + jkz*jkz + 1e-12f);
                    float r0k = sr[k];
                    float inj = 1.0f/fmaxf(r,   1e-8f);
                    float ink = 1.0f/fmaxf(r0k, 1e-8f);
                    float cs = (dx*vkx + dy*vky + dz*vkz) * inj * ink;
                    cs = fminf(fmaxf(cs, -1.0f), 1.0f);
                    pgeo[slot*4+0]=r; pgeo[slot*4+1]=r0k; pgeo[slot*4+2]=rjk; pgeo[slot*4+3]=cs;
                }
                rank++;
            }
        }
    }
}

// ---------------------------------------------------------------------------
// K2: geom MLP (353->256->256->64). 16 pair-rows per block, 512 blocks.
// ---------------------------------------------------------------------------
__launch_bounds__(256, 1)
__global__ void k_geom(const float* __restrict__ h, const int* __restrict__ jA, const int* __restrict__ kA,
                       const float* __restrict__ pmask, const float* __restrict__ pgeo,
                       const uint16_t* __restrict__ gW1p, const uint16_t* __restrict__ gW2p,
                       const uint16_t* __restrict__ gW3p,
                       const float* __restrict__ gb1, const float* __restrict__ gb2,
                       const float* __restrict__ gb3, float* __restrict__ ggeom){
    __shared__ __align__(16) char X0[16*768];   // 12288 B: features / later X2 [16][512B]
    __shared__ __align__(16) char X1[16*512];   // 8192 B
    const int b = blockIdx.x >> 4, pc = blockIdx.x & 15;
    const int tid = threadIdx.x;
    const int w = tid >> 6, l = tid & 63, l15 = l & 15, l4 = l >> 4;
    const int pbase = b*256 + pc*16;
    const float GAMMA = 26.694444444444443f;    // (31/6)^2
    const float STEP  = 0.19354838709677419f;   // 6/31

    // ---- build X0 [16 rows][384 cols] bf16 (swizzled) ----
    for (int e = tid; e < 16*96; e += 256){
        int row = e / 96;
        int q = e - row*96;
        int slot = pbase + row;
        float f0=0.f, f1=0.f, f2=0.f, f3=0.f;
        if (q < 64){
            int idxa = (q < 32) ? jA[slot] : kA[slot];
            int koff = (q < 32) ? (q*4) : (q*4 - 128);
            const float* hp = h + ((b*64 + idxa)*128 + koff);
            f0=hp[0]; f1=hp[1]; f2=hp[2]; f3=hp[3];
        } else if (q < 88){
            int kk = q*4 - 256;
            int reg = kk >> 5;
            int t0 = kk & 31;
            float rr = fminf(pgeo[slot*4 + reg], CUTOFF_F);
            float d0 = rr - (float)(t0+0)*STEP; f0 = __builtin_amdgcn_exp2f(-GAMMA*d0*d0*1.44269504088896f);
            float d1 = rr - (float)(t0+1)*STEP; f1 = __builtin_amdgcn_exp2f(-GAMMA*d1*d1*1.44269504088896f);
            float d2 = rr - (float)(t0+2)*STEP; f2 = __builtin_amdgcn_exp2f(-GAMMA*d2*d2*1.44269504088896f);
            float d3 = rr - (float)(t0+3)*STEP; f3 = __builtin_amdgcn_exp2f(-GAMMA*d3*d3*1.44269504088896f);
        } else if (q == 88){
            f0 = pgeo[slot*4+3];    // cosang; k=353..383 zero pad
        }
        uint32_t byte = (uint32_t)row*768u + (((uint32_t)(8*q)) ^ (((uint32_t)(row&7))<<4));
        *(uint2*)(X0 + byte) = make_uint2(pk2(f0,f1), pk2(f2,f3));
    }
    __syncthreads();

    // ---- GEMM1: [16 x 256], K=384 ----
    f32x4_t a1[4];
    #pragma unroll
    for (int nt=0; nt<4; nt++){ a1[nt][0]=0;a1[nt][1]=0;a1[nt][2]=0;a1[nt][3]=0; }
    #pragma unroll 3
    for (int kt=0; kt<12; kt++){
        int k0 = 4*l4 + 32*kt;
        int row = l15;
        uint32_t sw = ((uint32_t)(row&7))<<4;
        FragU A;
        frag_lds(A, X0, (uint32_t)row*768u + (((uint32_t)(2*k0))^sw),
                        (uint32_t)row*768u + (((uint32_t)(2*k0+32))^sw));
        FragU Bf[4];
        #pragma unroll
        for (int nt=0; nt<4; nt++)
            frag_gp(Bf[nt], gW1p + (64*w + 16*nt + l15)*384 + kt*32 + l4*8);
        __builtin_amdgcn_s_setprio(1);
        #pragma unroll
        for (int nt=0; nt<4; nt++)
            a1[nt] = __builtin_amdgcn_mfma_f32_16x16x32_bf16(A.v, Bf[nt].v, a1[nt], 0,0,0);
        __builtin_amdgcn_s_setprio(0);
    }
    #pragma unroll
    for (int nt=0; nt<4; nt++){
        int c = 64*w + 16*nt + l15;
        float bias = gb1[c];
        #pragma unroll
        for (int r=0; r<4; r++){
            int m = 4*l4 + r;
            float v = silu_f(a1[nt][r] + bias);
            uint32_t byte = (uint32_t)m*512u + (((uint32_t)(2*c)) ^ (((uint32_t)(m&7))<<4));
            *(uint16_t*)(X1 + byte) = f2bf(v);
        }
    }
    __syncthreads();

    // ---- GEMM2: [16 x 256], K=256 ----
    f32x4_t a2[4];
    #pragma unroll
    for (int nt=0; nt<4; nt++){ a2[nt][0]=0;a2[nt][1]=0;a2[nt][2]=0;a2[nt][3]=0; }
    #pragma unroll 2
    for (int kt=0; kt<8; kt++){
        int k0 = 4*l4 + 32*kt;
        int row = l15;
        uint32_t sw = ((uint32_t)(row&7))<<4;
        FragU A;
        frag_lds(A, X1, (uint32_t)row*512u + (((uint32_t)(2*k0))^sw),
                        (uint32_t)row*512u + (((uint32_t)(2*k0+32))^sw));
        FragU Bf[4];
        #pragma unroll
        for (int nt=0; nt<4; nt++)
            frag_gp(Bf[nt], gW2p + (64*w + 16*nt + l15)*256 + kt*32 + l4*8);
        __builtin_amdgcn_s_setprio(1);
        #pragma unroll
        for (int nt=0; nt<4; nt++)
            a2[nt] = __builtin_amdgcn_mfma_f32_16x16x32_bf16(A.v, Bf[nt].v, a2[nt], 0,0,0);
        __builtin_amdgcn_s_setprio(0);
    }
    #pragma unroll
    for (int nt=0; nt<4; nt++){
        int c = 64*w + 16*nt + l15;
        float bias = gb2[c];
        #pragma unroll
        for (int r=0; r<4; r++){
            int m = 4*l4 + r;
            float v = silu_f(a2[nt][r] + bias);
            uint32_t byte = (uint32_t)m*512u + (((uint32_t)(2*c)) ^ (((uint32_t)(m&7))<<4));
            *(uint16_t*)(X0 + byte) = f2bf(v);   // X2 lives in X0, stride 512B
        }
    }
    __syncthreads();

    // ---- GEMM3: [16 x 64], K=256; wave w owns cols 16w..16w+15 ----
    f32x4_t a3;
    a3[0]=0;a3[1]=0;a3[2]=0;a3[3]=0;
    int s = 16*w + l15;
    #pragma unroll 2
    for (int kt=0; kt<8; kt++){
        int k0 = 4*l4 + 32*kt;
        FragU Bf; frag_gp(Bf, gW3p + s*256 + kt*32 + l4*8);
        int row = l15;
        uint32_t sw = ((uint32_t)(row&7))<<4;
        FragU A;
        frag_lds(A, X0, (uint32_t)row*512u + (((uint32_t)(2*k0))^sw),
                        (uint32_t)row*512u + (((uint32_t)(2*k0+32))^sw));
        a3 = __builtin_amdgcn_mfma_f32_16x16x32_bf16(A.v, Bf.v, a3, 0,0,0);
    }
    float bias3 = gb3[s];
    #pragma unroll
    for (int r=0; r<4; r++){
        int prow = 4*l4 + r;
        int slot = pbase + prow;
        ggeom[slot*64 + s] = (a3[r] + bias3) * pmask[slot];
    }
}

// ---------------------------------------------------------------------------
// K3: main pe-MLP, 8-wave blocks. 256 blocks = (b, chunk of 32 pairs), 1/CU.
// Wave w: GEMM1 cols 32w..32w+31 (a1[4][2]); GEMM2 m-frag (w&3), K-half (w>>2).
// X1/X2 separate 32KB LDS buffers; 2 barriers/pair; split-K partials to pagg.
// ---------------------------------------------------------------------------
__launch_bounds__(512, 1)
__global__ void k_pe(const float* __restrict__ T_A, const float* __restrict__ T_B,
                     const float* __restrict__ T_C,
                     const uint16_t* __restrict__ W2p, const uint16_t* __restrict__ W3p,
                     const float* __restrict__ b2, const float* __restrict__ b3,
                     const int* __restrict__ zjA, const int* __restrict__ zkA,
                     const float* __restrict__ ggeom, float* __restrict__ pagg){
    __shared__ __align__(16) char X1s[64*512];   // 32768
    __shared__ __align__(16) char X2s[64*512];   // 32768
    const int b = blockIdx.x >> 3, pc = blockIdx.x & 7;
    const int tid = threadIdx.x;
    const int w = tid >> 6, l = tid & 63, l15 = l & 15, l4 = l >> 4;
    const int mw = w & 3, kth = w >> 2;

    float b2v[2], b3v[4];
    #pragma unroll
    for (int nt=0; nt<2; nt++) b2v[nt] = b2[32*w + 16*nt + l15];
    #pragma unroll
    for (int nt=0; nt<4; nt++) b3v[nt] = b3[16*nt + l15];
    const float hb = (kth == 0) ? 1.0f : 0.0f;   // bias added once across K-halves

    f32x4_t pacc[4];
    #pragma unroll
    for (int nt=0; nt<4; nt++){ pacc[nt][0]=0;pacc[nt][1]=0;pacc[nt][2]=0;pacc[nt][3]=0; }

    const int kb = tid & 63, nset = tid >> 6;   // X1-build roles: c-quad, n-octet
    const int k4 = kb*4;

    for (int pi = 0; pi < 32; pi++){
        const int slot = b*256 + pc*32 + pi;
        // ---- build X1 = silu(T_A[zj]+T_B[zk]+T_C[n]) -> X1s (bf16, swizzled) ----
        {
            int zj = zjA[slot], zk = zkA[slot];
            float4 ta = *(const float4*)(T_A + zj*256 + k4);
            float4 tb = *(const float4*)(T_B + zk*256 + k4);
            float bx = ta.x+tb.x, by = ta.y+tb.y, bz = ta.z+tb.z, bw = ta.w+tb.w;
            #pragma unroll
            for (int i = 0; i < 8; i++){
                int n = nset*8 + i;
                float4 tc = *(const float4*)(T_C + n*256 + k4);
                float v0 = silu_f(bx+tc.x), v1 = silu_f(by+tc.y);
                float v2 = silu_f(bz+tc.z), v3 = silu_f(bw+tc.w);
                uint32_t byte = (uint32_t)n*512u + (((uint32_t)(8*kb)) ^ (((uint32_t)(n&7))<<4));
                *(uint2*)(X1s + byte) = make_uint2(pk2(v0,v1), pk2(v2,v3));
            }
        }
        __syncthreads();   // bar1: X1 ready (also: all waves done GEMM2 of prev pair)
        // ---- GEMM1: [64 x 256], K=256; wave w owns cols 32w..32w+31 ----
        f32x4_t a1[4][2];
        #pragma unroll
        for (int mt=0; mt<4; mt++)
            #pragma unroll
            for (int nt=0; nt<2; nt++){ a1[mt][nt][0]=0;a1[mt][nt][1]=0;a1[mt][nt][2]=0;a1[mt][nt][3]=0; }
        #pragma unroll 2
        for (int kt=0; kt<8; kt++){
            int k0 = 4*l4 + 32*kt;
            FragU Bf[2];
            #pragma unroll
            for (int nt=0; nt<2; nt++)
                frag_gp(Bf[nt], W2p + (32*w + 16*nt + l15)*256 + kt*32 + l4*8);
            FragU A[4];
            #pragma unroll
            for (int mt=0; mt<4; mt++){
                int row = 16*mt + l15;
                uint32_t sw = ((uint32_t)(row&7))<<4;
                frag_lds(A[mt], X1s, (uint32_t)row*512u + (((uint32_t)(2*k0))^sw),
                                     (uint32_t)row*512u + (((uint32_t)(2*k0+32))^sw));
            }
            __builtin_amdgcn_s_setprio(1);
            #pragma unroll
            for (int nt=0; nt<2; nt++)
                #pragma unroll
                for (int mt=0; mt<4; mt++)
                    a1[mt][nt] = __builtin_amdgcn_mfma_f32_16x16x32_bf16(A[mt].v, Bf[nt].v, a1[mt][nt], 0,0,0);
            __builtin_amdgcn_s_setprio(0);
        }
        // ---- silu + store X2 (bf16) into X2s (separate buffer) ----
        #pragma unroll
        for (int nt=0; nt<2; nt++){
            int c = 32*w + 16*nt + l15;
            #pragma unroll
            for (int mt=0; mt<4; mt++)
                #pragma unroll
                for (int r=0; r<4; r++){
                    int m = 16*mt + 4*l4 + r;
                    float v = silu_f(a1[mt][nt][r] + b2v[nt]);
                    uint32_t byte = (uint32_t)m*512u + (((uint32_t)(2*c)) ^ (((uint32_t)(m&7))<<4));
                    *(uint16_t*)(X2s + byte) = f2bf(v);
                }
        }
        __syncthreads();   // bar2: X2 ready; X1 free for next build
        // ---- GEMM2 (split-K): rows 16mw..16mw+15, kt in [4kth, 4kth+4) ----
        f32x4_t a2[4];
        #pragma unroll
        for (int nt=0; nt<4; nt++){ a2[nt][0]=0;a2[nt][1]=0;a2[nt][2]=0;a2[nt][3]=0; }
        #pragma unroll
        for (int kk=0; kk<4; kk++){
            int kt = 4*kth + kk;
            int k0 = 4*l4 + 32*kt;
            FragU Wf[4];
            #pragma unroll
            for (int nt=0; nt<4; nt++)
                frag_gp(Wf[nt], W3p + (16*nt + l15)*256 + kt*32 + l4*8);
            int row = 16*mw + l15;
            uint32_t sw = ((uint32_t)(row&7))<<4;
            FragU A;
            frag_lds(A, X2s, (uint32_t)row*512u + (((uint32_t)(2*k0))^sw),
                             (uint32_t)row*512u + (((uint32_t)(2*k0+32))^sw));
            __builtin_amdgcn_s_setprio(1);
            #pragma unroll
            for (int nt=0; nt<4; nt++)
                a2[nt] = __builtin_amdgcn_mfma_f32_16x16x32_bf16(A.v, Wf[nt].v, a2[nt], 0,0,0);
            __builtin_amdgcn_s_setprio(0);
        }
        // ---- fuse: (g_elem partial) * g_geom, accumulate over pairs ----
        #pragma unroll
        for (int nt=0; nt<4; nt++){
            float gg = ggeom[slot*64 + 16*nt + l15];
            #pragma unroll
            for (int r=0; r<4; r++)
                pacc[nt][r] += (a2[nt][r] + b3v[nt]*hb) * gg;
        }
    }
    // ---- commit split-K partials: chunk = (b*8+pc)*2 + kth ----
    const int chunk = (b*8 + pc)*2 + kth;
    #pragma unroll
    for (int nt=0; nt<4; nt++)
        #pragma unroll
        for (int r=0; r<4; r++){
            int n = 16*mw + 4*l4 + r;
            int s = 16*nt + l15;
            pagg[(chunk*64 + n)*64 + s] = pacc[nt][r];
        }
}

// ---------------------------------------------------------------------------
// K4: agg = sum over 16 chunks; out = silu(agg @ op_W1 + b1) @ op_W2 + b2
// ---------------------------------------------------------------------------
__global__ void k_out(const float* __restrict__ pagg, const float* __restrict__ W1,
                      const float* __restrict__ bb1, const float* __restrict__ W2,
                      const float* __restrict__ bb2, float* __restrict__ out){
    __shared__ float sag[16][64];
    __shared__ float shid[16][256];
    const int row0 = blockIdx.x * 16;   // rows of [B*NE = 2048]
    const int tid = threadIdx.x;
    const int bb = row0 >> 6;           // 16-row block stays within one batch
    for (int i = tid; i < 16*64; i += 256){
        int row = row0 + (i >> 6);
        int nn = row & 63;
        int k = i & 63;
        float acc = 0.f;
        #pragma unroll
        for (int pcc = 0; pcc < 16; pcc++)
            acc += pagg[((bb*16 + pcc)*64 + nn)*64 + k];
        sag[i>>6][k] = acc;
    }
    __syncthreads();
    float a[16];
    #pragma unroll
    for (int i=0;i<16;i++) a[i] = bb1[tid];
    for (int k=0;k<64;k++){
        float wv = W1[k*256 + tid];
        #pragma unroll
        for (int i=0;i<16;i++) a[i] += sag[i][k]*wv;
    }
    #pragma unroll
    for (int i=0;i<16;i++) shid[i][tid] = silu_f(a[i]);
    __syncthreads();
    float o[16];
    #pragma unroll
    for (int i=0;i<16;i++) o[i] = bb2[tid];
    for (int c=0;c<256;c++){
        float wv = W2[c*256 + tid];
        #pragma unroll
        for (int i=0;i<16;i++) o[i] += shid[i][c]*wv;
    }
    #pragma unroll
    for (int i=0;i<16;i++) out[(row0+i)*256 + tid] = o[i];
}

// ---------------------------------------------------------------------------
extern "C" void kernel_launch(void* const* d_in, const int* in_sizes, int n_in,
                              void* d_out, int out_size, void* d_ws, size_t ws_size,
                              hipStream_t stream){
    const float* h      = (const float*)d_in[0];
    const int*   z      = (const int*)  d_in[1];
    const float* pos    = (const float*)d_in[2];
    const int*   mask   = (const int*)  d_in[3];
    const float* e_feat = (const float*)d_in[4];
    const float* z_emb  = (const float*)d_in[5];
    const float* gm_W1  = (const float*)d_in[6];
    const float* gm_b1  = (const float*)d_in[7];
    const float* gm_W2  = (const float*)d_in[8];
    const float* gm_b2  = (const float*)d_in[9];
    const float* gm_W3  = (const float*)d_in[10];
    const float* gm_b3  = (const float*)d_in[11];
    const float* pe_W1  = (const float*)d_in[12];
    const float* pe_b1  = (const float*)d_in[13];
    const float* pe_W2  = (const float*)d_in[14];
    const float* pe_b2  = (const float*)d_in[15];
    const float* pe_W3  = (const float*)d_in[16];
    const float* pe_b3  = (const float*)d_in[17];
    const float* op_W1  = (const float*)d_in[18];
    const float* op_b1  = (const float*)d_in[19];
    const float* op_W2  = (const float*)d_in[20];
    const float* op_b2  = (const float*)d_in[21];
    const int*   aidx   = (const int*)  d_in[22];
    float* out = (float*)d_out;
    char* ws = (char*)d_ws;

    // workspace layout (bytes, 16B-aligned)
    float*    T_A   = (float*)   (ws + 0);        // 103424
    float*    T_B   = (float*)   (ws + 103424);   // 103424
    float*    T_C   = (float*)   (ws + 206848);   // 65536
    uint16_t* W2p   = (uint16_t*)(ws + 272384);   // 131072
    uint16_t* W3p   = (uint16_t*)(ws + 403456);   // 32768
    uint16_t* gW1p  = (uint16_t*)(ws + 436224);   // 196608
    uint16_t* gW2p  = (uint16_t*)(ws + 632832);   // 131072
    uint16_t* gW3p  = (uint16_t*)(ws + 763904);   // 32768
    int*      jA    = (int*)     (ws + 796672);   // 32768
    int*      kA    = (int*)     (ws + 829440);
    int*      zjA   = (int*)     (ws + 862208);
    int*      zkA   = (int*)     (ws + 894976);
    float*    pmask = (float*)   (ws + 927744);
    float*    pgeo  = (float*)   (ws + 960512);   // 131072
    float*    ggeom = (float*)   (ws + 1091584);  // 2097152
    float*    pagg  = (float*)   (ws + 3188736);  // 8388608 (512 chunks x 64 x 64 f32)

    k_tables<<<266, 256, 0, stream>>>(z_emb, e_feat, pe_W1, pe_b1, T_A, T_B, T_C);
    k_prep<<<1024, 256, 0, stream>>>(pe_W2, pe_W3, gm_W1, gm_W2, gm_W3, W2p, W3p, gW1p, gW2p, gW3p);
    k_pairs<<<32, 64, 0, stream>>>(pos, mask, z, aidx, jA, kA, zjA, zkA, pmask, pgeo);
    k_geom<<<512, 256, 0, stream>>>(h, jA, kA, pmask, pgeo, gW1p, gW2p, gW3p,
                                    gm_b1, gm_b2, gm_b3, ggeom);
    k_pe<<<256, 512, 0, stream>>>(T_A, T_B, T_C, W2p, W3p, pe_b2, pe_b3,
                                  zjA, zkA, ggeom, pagg);
    k_out<<<128, 256, 0, stream>>>(pagg, op_W1, op_b1, op_W2, op_b2, out);
}